// Round 6
// baseline (2229.471 us; speedup 1.0000x reference)
//
#include <hip/hip_runtime.h>
#include <stdint.h>

#define A2B   1.8897259886f
#define R_MIN (0.5f * A2B)
#define R_MAX (4.0f * A2B)

// ---------------------------------------------------------------------------
// K1: per-edge rank assignment (one int atomic per edge) + pack target-elem q
// ---------------------------------------------------------------------------
__global__ void __launch_bounds__(256) k_rank(
        const int* __restrict__ src, const int* __restrict__ tgt,
        const int* __restrict__ elem, int* __restrict__ deg,
        unsigned short* __restrict__ packed, int E)
{
    int e = blockIdx.x * 256 + threadIdx.x;
    if (e >= E) return;
    int s = src[e];
    int q = elem[tgt[e]];
    int r = atomicAdd(deg + s, 1);          // rank of this edge within its src
    packed[e] = (unsigned short)(r | (q << 14));   // rank < 16384 guaranteed
}

// ---------------------------------------------------------------------------
// K2a/b/c: exclusive scan of deg[N] -> offs[N+1]
// ---------------------------------------------------------------------------
__global__ void __launch_bounds__(256) k_scan1(
        const int* __restrict__ deg, int* __restrict__ offs,
        int* __restrict__ bsum, int N)
{
    __shared__ int sd[256];
    int t = threadIdx.x, i = blockIdx.x * 256 + t;
    int v = (i < N) ? deg[i] : 0;
    sd[t] = v; __syncthreads();
    #pragma unroll
    for (int o = 1; o < 256; o <<= 1) {
        int x = (t >= o) ? sd[t - o] : 0;
        __syncthreads();
        sd[t] += x;
        __syncthreads();
    }
    if (i < N) offs[i] = sd[t] - v;                 // exclusive
    if (t == 255) bsum[blockIdx.x] = sd[255];       // block total
}

__global__ void __launch_bounds__(512) k_scan2(int* __restrict__ bsum, int NB)
{
    __shared__ int sd[512];
    int t = threadIdx.x;
    int v = (t < NB) ? bsum[t] : 0;
    sd[t] = v; __syncthreads();
    #pragma unroll
    for (int o = 1; o < 512; o <<= 1) {
        int x = (t >= o) ? sd[t - o] : 0;
        __syncthreads();
        sd[t] += x;
        __syncthreads();
    }
    if (t < NB) bsum[t] = sd[t] - v;                // exclusive block bases
}

__global__ void __launch_bounds__(256) k_scan3(
        int* __restrict__ offs, const int* __restrict__ bsum, int N, int E)
{
    int i = blockIdx.x * 256 + threadIdx.x;
    if (i < N) offs[i] += bsum[i >> 8];
    else if (i == N) offs[N] = E;
}

// ---------------------------------------------------------------------------
// K3: scatter 8B payload (dist, q) to CSR slot  [payload lives in d_out]
// ---------------------------------------------------------------------------
__global__ void __launch_bounds__(256) k_scatter(
        const int* __restrict__ src, const float* __restrict__ dist,
        const unsigned short* __restrict__ packed, const int* __restrict__ offs,
        float2* __restrict__ payload, int E)
{
    int e = blockIdx.x * 256 + threadIdx.x;
    if (e >= E) return;
    unsigned p = packed[e];
    int pos = offs[src[e]] + (int)(p & 0x3FFF);
    payload[pos] = make_float2(dist[e], __int_as_float((int)(p >> 14)));
}

// ---------------------------------------------------------------------------
// K4: gather, 8 lanes per node (edge-parallel), shfl-reduce, fused VQ + loss
//     Register budget: k-outer RBF accumulation keeps live set at
//     acc[16]+hid[16]+~10 temps (~50 VGPR) -- rbf[] never materializes.
//     (Rounds 4/5: rbf[16]+hid[16]+acc[16] fully-unrolled spilled at 64 AND
//     128 VGPR caps -> 4.2GB scratch traffic. This is the fix.)
// ---------------------------------------------------------------------------
__global__ void __launch_bounds__(256, 2) k_gather(
        const int* __restrict__ elem, const float* __restrict__ embed,
        const float* __restrict__ codebook,
        const float* __restrict__ fw1, const float* __restrict__ fb1,
        const float* __restrict__ fw2, const float* __restrict__ fb2,
        const int* __restrict__ offs, const float2* __restrict__ payload,
        int* __restrict__ atype, float* __restrict__ loss, int N)
{
    __shared__ float s_fw1[256], s_fw2[256], s_cb[256];
    __shared__ float s_fb1[16], s_fb2[16], s_emb[64], s_cbn[16];
    __shared__ float s_red[4];
    int t = threadIdx.x;
    s_fw1[t] = fw1[t];
    s_fw2[t] = fw2[t];
    s_cb[t]  = codebook[t];
    if (t < 16) { s_fb1[t] = fb1[t]; s_fb2[t] = fb2[t]; }
    if (t < 64) s_emb[t] = embed[t];
    __syncthreads();
    if (t < 16) {
        float s = 0.f;
        #pragma unroll
        for (int j = 0; j < 16; ++j) { float c = s_cb[t * 16 + j]; s += c * c; }
        s_cbn[t] = s;
    }
    __syncthreads();

    int node = blockIdx.x * 32 + (t >> 3);   // 8 lanes per node, 32 nodes/block
    int sub  = t & 7;
    float lp = 0.0f;
    if (node < N) {
        int o0 = offs[node], o1 = offs[node + 1];
        float acc[16];
        #pragma unroll
        for (int j = 0; j < 16; ++j) acc[j] = 0.f;

        const float step = (R_MAX - R_MIN) / 15.0f;
        const float invw = 16.0f / (R_MAX - R_MIN);
        for (int i = o0 + sub; i < o1; i += 8) {
            float2 pl = payload[i];
            float d = pl.x;
            int q = __float_as_int(pl.y);
            // layer 1, k-outer: hid[i] += rbf_k * fw1[i][k]; rbf_k dies fast
            float hid[16];
            #pragma unroll
            for (int i2 = 0; i2 < 16; ++i2) hid[i2] = s_fb1[i2];
            for (int k = 0; k < 16; ++k) {
                float u = (d - (R_MIN + (float)k * step)) * invw;
                float rk = __expf(-0.5f * u * u);
                #pragma unroll
                for (int i2 = 0; i2 < 16; ++i2)
                    hid[i2] += rk * s_fw1[i2 * 16 + k];   // LDS broadcast
            }
            #pragma unroll
            for (int i2 = 0; i2 < 16; ++i2) {
                float a = hid[i2];
                hid[i2] = a / (1.0f + __expf(-a));        // silu in place
            }
            const float* er = s_emb + q * 16;
            #pragma unroll
            for (int j = 0; j < 16; ++j) {
                float w = s_fb2[j];
                #pragma unroll
                for (int i2 = 0; i2 < 16; ++i2) w += hid[i2] * s_fw2[j * 16 + i2];
                acc[j] += w * er[j];                      // message = h[tgt] * W
            }
        }
        // 8-lane group reduction (lanes node-uniform; masks stay in-group)
        #pragma unroll
        for (int m = 1; m <= 4; m <<= 1) {
            #pragma unroll
            for (int j = 0; j < 16; ++j)
                acc[j] += __shfl_xor(acc[j], m, 64);
        }
        int qn = elem[node];
        float h[16], hh = 0.f;
        #pragma unroll
        for (int j = 0; j < 16; ++j) {
            h[j] = acc[j] + s_emb[qn * 16 + j];
            hh += h[j] * h[j];
        }
        float best = __builtin_inff(); int bi = 0;
        #pragma unroll
        for (int c = 0; c < 4; ++c) {
            int code = qn * 4 + c;
            float dot = 0.f;
            #pragma unroll
            for (int j = 0; j < 16; ++j) dot += h[j] * s_cb[code * 16 + j];
            float d2 = hh - 2.0f * dot + s_cbn[code];
            if (d2 < best) { best = d2; bi = code; }
        }
        if (sub == 0) {
            atype[node] = bi;
            #pragma unroll
            for (int j = 0; j < 16; ++j) {
                float df = h[j] - s_cb[bi * 16 + j];
                lp += df * df;
            }
        }
    }
    // block reduction of loss partials (lp nonzero only on sub==0 lanes)
    #pragma unroll
    for (int o = 32; o > 0; o >>= 1) lp += __shfl_down(lp, o, 64);
    int wid = t >> 6;
    if ((t & 63) == 0) s_red[wid] = lp;
    __syncthreads();
    if (t == 0) atomicAdd(loss, s_red[0] + s_red[1] + s_red[2] + s_red[3]);
}

// ---------------------------------------------------------------------------
// K5: build the 2560-entry (combo x pair) output table; finalize vq_loss
// ---------------------------------------------------------------------------
__global__ void __launch_bounds__(256) k_table(
        const float* __restrict__ codebook,
        const float* __restrict__ mw1, const float* __restrict__ mb1,
        const float* __restrict__ mw2, const float* __restrict__ mb2,
        const float* __restrict__ rD, const float* __restrict__ rA,
        const float* __restrict__ rR,
        const float* __restrict__ loss, float4* __restrict__ table,
        float* __restrict__ out_loss, float inv_nd)
{
    __shared__ float s_cb[256], s_mw1[256], s_mb1[16], s_mw2[48], s_mb2[3];
    __shared__ float s_rd[10], s_ra[10], s_rr[10];
    int tid = threadIdx.x;
    s_cb[tid] = codebook[tid];
    s_mw1[tid] = mw1[tid];
    if (tid < 16) s_mb1[tid] = mb1[tid];
    if (tid < 48) s_mw2[tid] = mw2[tid];
    if (tid < 3)  s_mb2[tid] = mb2[tid];
    if (tid < 10) { s_rd[tid] = rD[tid]; s_ra[tid] = rA[tid]; s_rr[tid] = rR[tid]; }
    __syncthreads();

    int a = tid >> 4, b = tid & 15;
    float pf[16];
    #pragma unroll
    for (int j = 0; j < 16; ++j) pf[j] = s_cb[a * 16 + j] + s_cb[b * 16 + j];
    float hid[16];
    #pragma unroll
    for (int i = 0; i < 16; ++i) {
        float acc = s_mb1[i];
        #pragma unroll
        for (int j = 0; j < 16; ++j) acc += pf[j] * s_mw1[i * 16 + j];
        hid[i] = acc / (1.0f + __expf(-acc));
    }
    float del[3];
    #pragma unroll
    for (int r = 0; r < 3; ++r) {
        float acc = s_mb2[r];
        #pragma unroll
        for (int i = 0; i < 16; ++i) acc += hid[i] * s_mw2[r * 16 + i];
        del[r] = acc;
    }
    #pragma unroll
    for (int p = 0; p < 10; ++p) {
        float xd = s_rd[p] + del[0];
        float xa = s_ra[p] + del[1];
        float De = (xd > 20.f) ? xd : log1pf(__expf(xd));   // softplus
        float al = (xa > 20.f) ? xa : log1pf(__expf(xa));
        float r0 = s_rr[p] + del[2];
        table[tid * 10 + p] = make_float4(De, al, r0, 0.f);
    }
    if (tid == 0) out_loss[0] = 0.25f * loss[0] * inv_nd;
}

// ---------------------------------------------------------------------------
// K6: per-edge output = table[(at[src]*16 + at[tgt])*10 + pair_idx]
// ---------------------------------------------------------------------------
__global__ void __launch_bounds__(256) k_out(
        const int* __restrict__ src, const int* __restrict__ tgt,
        const int* __restrict__ pidx, const int* __restrict__ atype,
        const float4* __restrict__ table, float2* __restrict__ out, int Ehalf)
{
    int i = blockIdx.x * 256 + threadIdx.x;
    if (i >= Ehalf) return;
    int2 s2 = ((const int2*)src)[i];
    int2 t2 = ((const int2*)tgt)[i];
    int2 p2 = ((const int2*)pidx)[i];
    int i0 = (atype[s2.x] * 16 + atype[t2.x]) * 10 + p2.x;
    int i1 = (atype[s2.y] * 16 + atype[t2.y]) * 10 + p2.y;
    float4 t0 = table[i0];
    float4 t1 = table[i1];
    float2* op = out + (size_t)3 * i;
    op[0] = make_float2(t0.x, t0.y);
    op[1] = make_float2(t0.z, t1.x);
    op[2] = make_float2(t1.y, t1.z);
}

// ---------------------------------------------------------------------------
extern "C" void kernel_launch(void* const* d_in, const int* in_sizes, int n_in,
                              void* d_out, int out_size, void* d_ws, size_t ws_size,
                              hipStream_t stream)
{
    (void)n_in; (void)out_size;
    const int*   elem  = (const int*)d_in[0];
    const int*   eidx  = (const int*)d_in[1];
    const float* dist  = (const float*)d_in[2];
    const int*   pidx  = (const int*)d_in[3];
    const float* embed = (const float*)d_in[4];
    const float* fw1   = (const float*)d_in[5];
    const float* fb1   = (const float*)d_in[6];
    const float* fw2   = (const float*)d_in[7];
    const float* fb2   = (const float*)d_in[8];
    const float* mw1   = (const float*)d_in[9];
    const float* mb1   = (const float*)d_in[10];
    const float* mw2   = (const float*)d_in[11];
    const float* mb2   = (const float*)d_in[12];
    const float* cb    = (const float*)d_in[13];
    const float* rD    = (const float*)d_in[14];
    const float* rA    = (const float*)d_in[15];
    const float* rR    = (const float*)d_in[16];

    int N = in_sizes[0];
    int E = in_sizes[2];
    const int* src = eidx;
    const int* tgt = eidx + E;
    int NB = (N + 255) / 256;
    if (NB > 512) return;                       // scan assumes <=512 blocks

    // ---- workspace layout ----
    char* ws = (char*)d_ws;
    size_t cur = 0;
    int*   deg   = (int*)(ws + cur);  cur += (size_t)N * 4;
    float* loss  = (float*)(ws + cur); cur += 4;           // memset with deg
    size_t clearB = cur;
    int*   offs  = (int*)(ws + cur);  cur += (size_t)(N + 1) * 4;
    int*   bsum  = (int*)(ws + cur);  cur += 512 * 4;
    int*   atype = (int*)(ws + cur);  cur += (size_t)N * 4;
    unsigned short* packed = (unsigned short*)(ws + cur); cur += (size_t)E * 2;
    cur = (cur + 15) & ~(size_t)15;
    float4* table = (float4*)(ws + cur); cur += 2560 * sizeof(float4);
    if (ws_size < cur) return;

    float2* payload = (float2*)d_out;           // 25.6MB scratch inside d_out

    hipMemsetAsync(d_ws, 0, clearB, stream);    // deg + loss

    k_rank<<<(E + 255) / 256, 256, 0, stream>>>(src, tgt, elem, deg, packed, E);
    k_scan1<<<NB, 256, 0, stream>>>(deg, offs, bsum, N);
    k_scan2<<<1, 512, 0, stream>>>(bsum, NB);
    k_scan3<<<(N + 256) / 256, 256, 0, stream>>>(offs, bsum, N, E);
    k_scatter<<<(E + 255) / 256, 256, 0, stream>>>(src, dist, packed, offs,
                                                   payload, E);
    int NB2 = (N + 31) / 32;                    // 32 nodes per block (8 lanes/node)
    k_gather<<<NB2, 256, 0, stream>>>(elem, embed, cb, fw1, fb1, fw2, fb2,
                                      offs, payload, atype, loss, N);
    float* outl = (float*)d_out + (size_t)3 * E;
    k_table<<<1, 256, 0, stream>>>(cb, mw1, mb1, mw2, mb2, rD, rA, rR,
                                   loss, table, outl,
                                   1.0f / (float)((size_t)N * 16));
    k_out<<<(E / 2 + 255) / 256, 256, 0, stream>>>(src, tgt, pidx, atype, table,
                                                   (float2*)d_out, E / 2);
}

// Round 7
// 709.728 us; speedup vs baseline: 3.1413x; 3.1413x over previous
//
#include <hip/hip_runtime.h>
#include <stdint.h>

#define A2B   1.8897259886f
#define R_MIN (0.5f * A2B)
#define R_MAX (4.0f * A2B)

// ---------------------------------------------------------------------------
// K1: per-edge rank assignment (one int atomic per edge) + pack target-elem q
// ---------------------------------------------------------------------------
__global__ void __launch_bounds__(256) k_rank(
        const int* __restrict__ src, const int* __restrict__ tgt,
        const int* __restrict__ elem, int* __restrict__ deg,
        unsigned short* __restrict__ packed, int E)
{
    int e = blockIdx.x * 256 + threadIdx.x;
    if (e >= E) return;
    int s = src[e];
    int q = elem[tgt[e]];
    int r = atomicAdd(deg + s, 1);          // rank of this edge within its src
    packed[e] = (unsigned short)(r | (q << 14));   // rank < 16384 guaranteed
}

// ---------------------------------------------------------------------------
// K2a/b/c: exclusive scan of deg[N] -> offs[N+1]
// ---------------------------------------------------------------------------
__global__ void __launch_bounds__(256) k_scan1(
        const int* __restrict__ deg, int* __restrict__ offs,
        int* __restrict__ bsum, int N)
{
    __shared__ int sd[256];
    int t = threadIdx.x, i = blockIdx.x * 256 + t;
    int v = (i < N) ? deg[i] : 0;
    sd[t] = v; __syncthreads();
    #pragma unroll
    for (int o = 1; o < 256; o <<= 1) {
        int x = (t >= o) ? sd[t - o] : 0;
        __syncthreads();
        sd[t] += x;
        __syncthreads();
    }
    if (i < N) offs[i] = sd[t] - v;                 // exclusive
    if (t == 255) bsum[blockIdx.x] = sd[255];       // block total
}

__global__ void __launch_bounds__(512) k_scan2(int* __restrict__ bsum, int NB)
{
    __shared__ int sd[512];
    int t = threadIdx.x;
    int v = (t < NB) ? bsum[t] : 0;
    sd[t] = v; __syncthreads();
    #pragma unroll
    for (int o = 1; o < 512; o <<= 1) {
        int x = (t >= o) ? sd[t - o] : 0;
        __syncthreads();
        sd[t] += x;
        __syncthreads();
    }
    if (t < NB) bsum[t] = sd[t] - v;                // exclusive block bases
}

__global__ void __launch_bounds__(256) k_scan3(
        int* __restrict__ offs, const int* __restrict__ bsum, int N, int E)
{
    int i = blockIdx.x * 256 + threadIdx.x;
    if (i < N) offs[i] += bsum[i >> 8];
    else if (i == N) offs[N] = E;
}

// ---------------------------------------------------------------------------
// K3: scatter 8B payload (dist, q) to CSR slot  [payload lives in d_out]
// ---------------------------------------------------------------------------
__global__ void __launch_bounds__(256) k_scatter(
        const int* __restrict__ src, const float* __restrict__ dist,
        const unsigned short* __restrict__ packed, const int* __restrict__ offs,
        float2* __restrict__ payload, int E)
{
    int e = blockIdx.x * 256 + threadIdx.x;
    if (e >= E) return;
    unsigned p = packed[e];
    int pos = offs[src[e]] + (int)(p & 0x3FFF);
    payload[pos] = make_float2(dist[e], __int_as_float((int)(p >> 14)));
}

// ---------------------------------------------------------------------------
// K4: gather, 8 lanes per node (edge-parallel), shfl-reduce, fused VQ + loss
//     REGISTER NOTE (rounds 4/5/6): ANY min-waves cap ((256,4)->64 VGPR,
//     (256,2)->128 VGPR) made the allocator spill ~1.3KB/edge -> 3-4 GB
//     scratch traffic, 5% VALUBusy. Round 3 proved the same MLP body is
//     spill-free when the allocator is left free (VGPR=256, FETCH 30MB).
//     So: plain launch_bounds(256), no min-waves arg. k-loop unroll(disable)
//     keeps the LDS-load live ranges short.
// ---------------------------------------------------------------------------
__global__ void __launch_bounds__(256) k_gather(
        const int* __restrict__ elem, const float* __restrict__ embed,
        const float* __restrict__ codebook,
        const float* __restrict__ fw1, const float* __restrict__ fb1,
        const float* __restrict__ fw2, const float* __restrict__ fb2,
        const int* __restrict__ offs, const float2* __restrict__ payload,
        int* __restrict__ atype, float* __restrict__ loss, int N)
{
    __shared__ float s_fw1[256], s_fw2[256], s_cb[256];
    __shared__ float s_fb1[16], s_fb2[16], s_emb[64], s_cbn[16];
    __shared__ float s_red[4];
    int t = threadIdx.x;
    s_fw1[t] = fw1[t];
    s_fw2[t] = fw2[t];
    s_cb[t]  = codebook[t];
    if (t < 16) { s_fb1[t] = fb1[t]; s_fb2[t] = fb2[t]; }
    if (t < 64) s_emb[t] = embed[t];
    __syncthreads();
    if (t < 16) {
        float s = 0.f;
        #pragma unroll
        for (int j = 0; j < 16; ++j) { float c = s_cb[t * 16 + j]; s += c * c; }
        s_cbn[t] = s;
    }
    __syncthreads();

    int node = blockIdx.x * 32 + (t >> 3);   // 8 lanes per node, 32 nodes/block
    int sub  = t & 7;
    float lp = 0.0f;
    if (node < N) {
        int o0 = offs[node], o1 = offs[node + 1];
        float acc[16];
        #pragma unroll
        for (int j = 0; j < 16; ++j) acc[j] = 0.f;

        const float step = (R_MAX - R_MIN) / 15.0f;
        const float invw = 16.0f / (R_MAX - R_MIN);
        for (int i = o0 + sub; i < o1; i += 8) {
            float2 pl = payload[i];
            float d = pl.x;
            int q = __float_as_int(pl.y);
            // layer 1, k-outer: hid[i] += rbf_k * fw1[i][k]; rbf_k dies fast
            float hid[16];
            #pragma unroll
            for (int i2 = 0; i2 < 16; ++i2) hid[i2] = s_fb1[i2];
            #pragma clang loop unroll(disable)
            for (int k = 0; k < 16; ++k) {
                float u = (d - (R_MIN + (float)k * step)) * invw;
                float rk = __expf(-0.5f * u * u);
                #pragma unroll
                for (int i2 = 0; i2 < 16; ++i2)
                    hid[i2] += rk * s_fw1[i2 * 16 + k];   // LDS broadcast
            }
            #pragma unroll
            for (int i2 = 0; i2 < 16; ++i2) {
                float a = hid[i2];
                hid[i2] = a / (1.0f + __expf(-a));        // silu in place
            }
            const float* er = s_emb + q * 16;
            #pragma unroll
            for (int j = 0; j < 16; ++j) {
                float w = s_fb2[j];
                #pragma unroll
                for (int i2 = 0; i2 < 16; ++i2) w += hid[i2] * s_fw2[j * 16 + i2];
                acc[j] += w * er[j];                      // message = h[tgt] * W
            }
        }
        // 8-lane group reduction (lanes node-uniform; masks stay in-group)
        #pragma unroll
        for (int m = 1; m <= 4; m <<= 1) {
            #pragma unroll
            for (int j = 0; j < 16; ++j)
                acc[j] += __shfl_xor(acc[j], m, 64);
        }
        int qn = elem[node];
        float h[16], hh = 0.f;
        #pragma unroll
        for (int j = 0; j < 16; ++j) {
            h[j] = acc[j] + s_emb[qn * 16 + j];
            hh += h[j] * h[j];
        }
        float best = __builtin_inff(); int bi = 0;
        #pragma unroll
        for (int c = 0; c < 4; ++c) {
            int code = qn * 4 + c;
            float dot = 0.f;
            #pragma unroll
            for (int j = 0; j < 16; ++j) dot += h[j] * s_cb[code * 16 + j];
            float d2 = hh - 2.0f * dot + s_cbn[code];
            if (d2 < best) { best = d2; bi = code; }
        }
        if (sub == 0) {
            atype[node] = bi;
            #pragma unroll
            for (int j = 0; j < 16; ++j) {
                float df = h[j] - s_cb[bi * 16 + j];
                lp += df * df;
            }
        }
    }
    // block reduction of loss partials (lp nonzero only on sub==0 lanes)
    #pragma unroll
    for (int o = 32; o > 0; o >>= 1) lp += __shfl_down(lp, o, 64);
    int wid = t >> 6;
    if ((t & 63) == 0) s_red[wid] = lp;
    __syncthreads();
    if (t == 0) atomicAdd(loss, s_red[0] + s_red[1] + s_red[2] + s_red[3]);
}

// ---------------------------------------------------------------------------
// K5: build the 2560-entry (combo x pair) output table; finalize vq_loss
// ---------------------------------------------------------------------------
__global__ void __launch_bounds__(256) k_table(
        const float* __restrict__ codebook,
        const float* __restrict__ mw1, const float* __restrict__ mb1,
        const float* __restrict__ mw2, const float* __restrict__ mb2,
        const float* __restrict__ rD, const float* __restrict__ rA,
        const float* __restrict__ rR,
        const float* __restrict__ loss, float4* __restrict__ table,
        float* __restrict__ out_loss, float inv_nd)
{
    __shared__ float s_cb[256], s_mw1[256], s_mb1[16], s_mw2[48], s_mb2[3];
    __shared__ float s_rd[10], s_ra[10], s_rr[10];
    int tid = threadIdx.x;
    s_cb[tid] = codebook[tid];
    s_mw1[tid] = mw1[tid];
    if (tid < 16) s_mb1[tid] = mb1[tid];
    if (tid < 48) s_mw2[tid] = mw2[tid];
    if (tid < 3)  s_mb2[tid] = mb2[tid];
    if (tid < 10) { s_rd[tid] = rD[tid]; s_ra[tid] = rA[tid]; s_rr[tid] = rR[tid]; }
    __syncthreads();

    int a = tid >> 4, b = tid & 15;
    float pf[16];
    #pragma unroll
    for (int j = 0; j < 16; ++j) pf[j] = s_cb[a * 16 + j] + s_cb[b * 16 + j];
    float hid[16];
    #pragma unroll
    for (int i = 0; i < 16; ++i) {
        float acc = s_mb1[i];
        #pragma unroll
        for (int j = 0; j < 16; ++j) acc += pf[j] * s_mw1[i * 16 + j];
        hid[i] = acc / (1.0f + __expf(-acc));
    }
    float del[3];
    #pragma unroll
    for (int r = 0; r < 3; ++r) {
        float acc = s_mb2[r];
        #pragma unroll
        for (int i = 0; i < 16; ++i) acc += hid[i] * s_mw2[r * 16 + i];
        del[r] = acc;
    }
    #pragma unroll
    for (int p = 0; p < 10; ++p) {
        float xd = s_rd[p] + del[0];
        float xa = s_ra[p] + del[1];
        float De = (xd > 20.f) ? xd : log1pf(__expf(xd));   // softplus
        float al = (xa > 20.f) ? xa : log1pf(__expf(xa));
        float r0 = s_rr[p] + del[2];
        table[tid * 10 + p] = make_float4(De, al, r0, 0.f);
    }
    if (tid == 0) out_loss[0] = 0.25f * loss[0] * inv_nd;
}

// ---------------------------------------------------------------------------
// K6: per-edge output = table[(at[src]*16 + at[tgt])*10 + pair_idx]
// ---------------------------------------------------------------------------
__global__ void __launch_bounds__(256) k_out(
        const int* __restrict__ src, const int* __restrict__ tgt,
        const int* __restrict__ pidx, const int* __restrict__ atype,
        const float4* __restrict__ table, float2* __restrict__ out, int Ehalf)
{
    int i = blockIdx.x * 256 + threadIdx.x;
    if (i >= Ehalf) return;
    int2 s2 = ((const int2*)src)[i];
    int2 t2 = ((const int2*)tgt)[i];
    int2 p2 = ((const int2*)pidx)[i];
    int i0 = (atype[s2.x] * 16 + atype[t2.x]) * 10 + p2.x;
    int i1 = (atype[s2.y] * 16 + atype[t2.y]) * 10 + p2.y;
    float4 t0 = table[i0];
    float4 t1 = table[i1];
    float2* op = out + (size_t)3 * i;
    op[0] = make_float2(t0.x, t0.y);
    op[1] = make_float2(t0.z, t1.x);
    op[2] = make_float2(t1.y, t1.z);
}

// ---------------------------------------------------------------------------
extern "C" void kernel_launch(void* const* d_in, const int* in_sizes, int n_in,
                              void* d_out, int out_size, void* d_ws, size_t ws_size,
                              hipStream_t stream)
{
    (void)n_in; (void)out_size;
    const int*   elem  = (const int*)d_in[0];
    const int*   eidx  = (const int*)d_in[1];
    const float* dist  = (const float*)d_in[2];
    const int*   pidx  = (const int*)d_in[3];
    const float* embed = (const float*)d_in[4];
    const float* fw1   = (const float*)d_in[5];
    const float* fb1   = (const float*)d_in[6];
    const float* fw2   = (const float*)d_in[7];
    const float* fb2   = (const float*)d_in[8];
    const float* mw1   = (const float*)d_in[9];
    const float* mb1   = (const float*)d_in[10];
    const float* mw2   = (const float*)d_in[11];
    const float* mb2   = (const float*)d_in[12];
    const float* cb    = (const float*)d_in[13];
    const float* rD    = (const float*)d_in[14];
    const float* rA    = (const float*)d_in[15];
    const float* rR    = (const float*)d_in[16];

    int N = in_sizes[0];
    int E = in_sizes[2];
    const int* src = eidx;
    const int* tgt = eidx + E;
    int NB = (N + 255) / 256;
    if (NB > 512) return;                       // scan assumes <=512 blocks

    // ---- workspace layout ----
    char* ws = (char*)d_ws;
    size_t cur = 0;
    int*   deg   = (int*)(ws + cur);  cur += (size_t)N * 4;
    float* loss  = (float*)(ws + cur); cur += 4;           // memset with deg
    size_t clearB = cur;
    int*   offs  = (int*)(ws + cur);  cur += (size_t)(N + 1) * 4;
    int*   bsum  = (int*)(ws + cur);  cur += 512 * 4;
    int*   atype = (int*)(ws + cur);  cur += (size_t)N * 4;
    unsigned short* packed = (unsigned short*)(ws + cur); cur += (size_t)E * 2;
    cur = (cur + 15) & ~(size_t)15;
    float4* table = (float4*)(ws + cur); cur += 2560 * sizeof(float4);
    if (ws_size < cur) return;

    float2* payload = (float2*)d_out;           // 25.6MB scratch inside d_out

    hipMemsetAsync(d_ws, 0, clearB, stream);    // deg + loss

    k_rank<<<(E + 255) / 256, 256, 0, stream>>>(src, tgt, elem, deg, packed, E);
    k_scan1<<<NB, 256, 0, stream>>>(deg, offs, bsum, N);
    k_scan2<<<1, 512, 0, stream>>>(bsum, NB);
    k_scan3<<<(N + 256) / 256, 256, 0, stream>>>(offs, bsum, N, E);
    k_scatter<<<(E + 255) / 256, 256, 0, stream>>>(src, dist, packed, offs,
                                                   payload, E);
    int NB2 = (N + 31) / 32;                    // 32 nodes per block (8 lanes/node)
    k_gather<<<NB2, 256, 0, stream>>>(elem, embed, cb, fw1, fb1, fw2, fb2,
                                      offs, payload, atype, loss, N);
    float* outl = (float*)d_out + (size_t)3 * E;
    k_table<<<1, 256, 0, stream>>>(cb, mw1, mb1, mw2, mb2, rD, rA, rR,
                                   loss, table, outl,
                                   1.0f / (float)((size_t)N * 16));
    k_out<<<(E / 2 + 255) / 256, 256, 0, stream>>>(src, tgt, pidx, atype, table,
                                                   (float2*)d_out, E / 2);
}

// Round 8
// 396.637 us; speedup vs baseline: 5.6209x; 1.7894x over previous
//
#include <hip/hip_runtime.h>
#include <stdint.h>

#define A2B   1.8897259886f
#define R_MIN (0.5f * A2B)
#define R_MAX (4.0f * A2B)

// ---------------------------------------------------------------------------
// K1: per-edge rank within (src, elem[tgt]) bin -- one int atomic per edge
// ---------------------------------------------------------------------------
__global__ void __launch_bounds__(256) k_rank(
        const int* __restrict__ src, const int* __restrict__ tgt,
        const int* __restrict__ elem, int* __restrict__ deg4,
        unsigned short* __restrict__ packed, int E)
{
    int e = blockIdx.x * 256 + threadIdx.x;
    if (e >= E) return;
    int s = src[e];
    int q = elem[tgt[e]];
    int r = atomicAdd(deg4 + s * 4 + q, 1);        // rank within (node,q) bin
    packed[e] = (unsigned short)(r | (q << 12));   // r < 4096 (mean bin = 8)
}

// ---------------------------------------------------------------------------
// K2a/b/c: exclusive scan of deg4[N4] -> offs4[N4+1]
// ---------------------------------------------------------------------------
__global__ void __launch_bounds__(256) k_scan1(
        const int* __restrict__ deg, int* __restrict__ offs,
        int* __restrict__ bsum, int N4)
{
    __shared__ int sd[256];
    int t = threadIdx.x, i = blockIdx.x * 256 + t;
    int v = (i < N4) ? deg[i] : 0;
    sd[t] = v; __syncthreads();
    #pragma unroll
    for (int o = 1; o < 256; o <<= 1) {
        int x = (t >= o) ? sd[t - o] : 0;
        __syncthreads();
        sd[t] += x;
        __syncthreads();
    }
    if (i < N4) offs[i] = sd[t] - v;                // exclusive
    if (t == 255) bsum[blockIdx.x] = sd[255];       // block total
}

// chunked single-block scan: handles NB up to 2048 block-sums
__global__ void __launch_bounds__(256) k_scan2(int* __restrict__ bsum, int NB)
{
    __shared__ int sd[256];
    __shared__ int carry;
    int t = threadIdx.x;
    if (t == 0) carry = 0;
    __syncthreads();
    for (int base = 0; base < NB; base += 256) {
        int i = base + t;
        int v = (i < NB) ? bsum[i] : 0;
        sd[t] = v; __syncthreads();
        #pragma unroll
        for (int o = 1; o < 256; o <<= 1) {
            int x = (t >= o) ? sd[t - o] : 0;
            __syncthreads();
            sd[t] += x;
            __syncthreads();
        }
        int c = carry;                              // uniform read
        if (i < NB) bsum[i] = c + sd[t] - v;        // exclusive block base
        __syncthreads();
        if (t == 255) carry = c + sd[255];
        __syncthreads();
    }
}

__global__ void __launch_bounds__(256) k_scan3(
        int* __restrict__ offs, const int* __restrict__ bsum, int N4, int E)
{
    int i = blockIdx.x * 256 + threadIdx.x;
    if (i < N4) offs[i] += bsum[i >> 8];
    else if (i == N4) offs[N4] = E;
}

// ---------------------------------------------------------------------------
// K3: scatter 4B payload (dist) to (node,q)-binned CSR slot [lives in d_out]
// ---------------------------------------------------------------------------
__global__ void __launch_bounds__(256) k_scatter(
        const int* __restrict__ src, const float* __restrict__ dist,
        const unsigned short* __restrict__ packed, const int* __restrict__ offs4,
        float* __restrict__ payload, int E)
{
    int e = blockIdx.x * 256 + threadIdx.x;
    if (e >= E) return;
    unsigned p = packed[e];
    int q = (int)(p >> 12);
    int pos = offs4[src[e] * 4 + q] + (int)(p & 0xFFF);
    payload[pos] = dist[e];
}

// ---------------------------------------------------------------------------
// K4: gather, 8 lanes/node, (node,q)-binned edges.
//     Per edge: layer 1 only (G += silu(fw1@rbf+fb1)); layer 2 is AFFINE so
//     it's applied once per bin to the per-lane partial G (exact by
//     linearity), with the n_bin*fb2 count-term added on lane 0.
//     fw1 staged TRANSPOSED so layer-1 weight reads are ds_read_b128.
//     Register note (r4-r7): no min-waves cap (caps forced spills); live set
//     here is acc[16]+G[16]+g[16]+temps ~ 60.
// ---------------------------------------------------------------------------
__global__ void __launch_bounds__(256) k_gather(
        const int* __restrict__ elem, const float* __restrict__ embed,
        const float* __restrict__ codebook,
        const float* __restrict__ fw1, const float* __restrict__ fb1,
        const float* __restrict__ fw2, const float* __restrict__ fb2,
        const int* __restrict__ offs4, const float* __restrict__ payload,
        int* __restrict__ atype, float* __restrict__ loss, int N)
{
    __shared__ float4 s_fw1t[64];   // [k][i2/4]: fw1t[k][i2] = fw1[i2][k]
    __shared__ float4 s_fw2v[64];   // [j][i2/4]
    __shared__ float s_cb[256];
    __shared__ float s_fb1[16], s_fb2[16], s_emb[64], s_cbn[16];
    __shared__ float s_red[4];
    int t = threadIdx.x;
    {
        float* f1 = (float*)s_fw1t;
        f1[(t & 15) * 16 + (t >> 4)] = fw1[t];     // transpose on stage
        float* f2 = (float*)s_fw2v;
        f2[t] = fw2[t];
        s_cb[t] = codebook[t];
    }
    if (t < 16) { s_fb1[t] = fb1[t]; s_fb2[t] = fb2[t]; }
    if (t < 64) s_emb[t] = embed[t];
    __syncthreads();
    if (t < 16) {
        float s = 0.f;
        #pragma unroll
        for (int j = 0; j < 16; ++j) { float c = s_cb[t * 16 + j]; s += c * c; }
        s_cbn[t] = s;
    }
    __syncthreads();

    int node = blockIdx.x * 32 + (t >> 3);   // 8 lanes per node
    int sub  = t & 7;
    float lp = 0.0f;
    float acc[16];
    #pragma unroll
    for (int j = 0; j < 16; ++j) acc[j] = 0.f;

    if (node < N) {
        const float step = (R_MAX - R_MIN) / 15.0f;
        const float invw = 16.0f / (R_MAX - R_MIN);
        #pragma clang loop unroll(disable)
        for (int qq = 0; qq < 4; ++qq) {
            int b0 = offs4[node * 4 + qq], b1 = offs4[node * 4 + qq + 1];
            if (b0 == b1) continue;
            float G[16];
            #pragma unroll
            for (int j = 0; j < 16; ++j) G[j] = 0.f;
            for (int i = b0 + sub; i < b1; i += 8) {
                float d = payload[i];
                float g[16];
                #pragma unroll
                for (int i2 = 0; i2 < 16; ++i2) g[i2] = s_fb1[i2];
                #pragma clang loop unroll(disable)
                for (int k = 0; k < 16; ++k) {
                    float u = (d - (R_MIN + (float)k * step)) * invw;
                    float rk = __expf(-0.5f * u * u);
                    float4 w0 = s_fw1t[k*4+0], w1 = s_fw1t[k*4+1];
                    float4 w2 = s_fw1t[k*4+2], w3 = s_fw1t[k*4+3];
                    g[0]+=rk*w0.x;  g[1]+=rk*w0.y;  g[2]+=rk*w0.z;  g[3]+=rk*w0.w;
                    g[4]+=rk*w1.x;  g[5]+=rk*w1.y;  g[6]+=rk*w1.z;  g[7]+=rk*w1.w;
                    g[8]+=rk*w2.x;  g[9]+=rk*w2.y;  g[10]+=rk*w2.z; g[11]+=rk*w2.w;
                    g[12]+=rk*w3.x; g[13]+=rk*w3.y; g[14]+=rk*w3.z; g[15]+=rk*w3.w;
                }
                #pragma unroll
                for (int i2 = 0; i2 < 16; ++i2) {
                    float a = g[i2];
                    G[i2] += a / (1.0f + __expf(-a));      // silu
                }
            }
            // layer 2 once per bin on per-lane partial G (exact: L2 affine)
            const float* er = s_emb + qq * 16;
            #pragma clang loop unroll_count(4)
            for (int j = 0; j < 16; ++j) {
                float4 f0 = s_fw2v[j*4+0], f1 = s_fw2v[j*4+1];
                float4 f2 = s_fw2v[j*4+2], f3 = s_fw2v[j*4+3];
                float w = G[0]*f0.x  + G[1]*f0.y  + G[2]*f0.z  + G[3]*f0.w
                        + G[4]*f1.x  + G[5]*f1.y  + G[6]*f1.z  + G[7]*f1.w
                        + G[8]*f2.x  + G[9]*f2.y  + G[10]*f2.z + G[11]*f2.w
                        + G[12]*f3.x + G[13]*f3.y + G[14]*f3.z + G[15]*f3.w;
                acc[j] += w * er[j];
            }
            if (sub == 0) {
                float nb = (float)(b1 - b0);
                #pragma unroll
                for (int j = 0; j < 16; ++j)
                    acc[j] += nb * s_fb2[j] * er[j];       // count term
            }
        }
        // 8-lane group reduction
        #pragma unroll
        for (int m = 1; m <= 4; m <<= 1) {
            #pragma unroll
            for (int j = 0; j < 16; ++j)
                acc[j] += __shfl_xor(acc[j], m, 64);
        }
        int qn = elem[node];
        float h[16], hh = 0.f;
        #pragma unroll
        for (int j = 0; j < 16; ++j) {
            h[j] = acc[j] + s_emb[qn * 16 + j];
            hh += h[j] * h[j];
        }
        float best = __builtin_inff(); int bi = 0;
        #pragma unroll
        for (int c = 0; c < 4; ++c) {
            int code = qn * 4 + c;
            float dot = 0.f;
            #pragma unroll
            for (int j = 0; j < 16; ++j) dot += h[j] * s_cb[code * 16 + j];
            float d2 = hh - 2.0f * dot + s_cbn[code];
            if (d2 < best) { best = d2; bi = code; }
        }
        if (sub == 0) {
            atype[node] = bi;
            #pragma unroll
            for (int j = 0; j < 16; ++j) {
                float df = h[j] - s_cb[bi * 16 + j];
                lp += df * df;
            }
        }
    }
    // block reduction of loss partials
    #pragma unroll
    for (int o = 32; o > 0; o >>= 1) lp += __shfl_down(lp, o, 64);
    int wid = t >> 6;
    if ((t & 63) == 0) s_red[wid] = lp;
    __syncthreads();
    if (t == 0) atomicAdd(loss, s_red[0] + s_red[1] + s_red[2] + s_red[3]);
}

// ---------------------------------------------------------------------------
// K5: build the 2560-entry (combo x pair) output table; finalize vq_loss
// ---------------------------------------------------------------------------
__global__ void __launch_bounds__(256) k_table(
        const float* __restrict__ codebook,
        const float* __restrict__ mw1, const float* __restrict__ mb1,
        const float* __restrict__ mw2, const float* __restrict__ mb2,
        const float* __restrict__ rD, const float* __restrict__ rA,
        const float* __restrict__ rR,
        const float* __restrict__ loss, float4* __restrict__ table,
        float* __restrict__ out_loss, float inv_nd)
{
    __shared__ float s_cb[256], s_mw1[256], s_mb1[16], s_mw2[48], s_mb2[3];
    __shared__ float s_rd[10], s_ra[10], s_rr[10];
    int tid = threadIdx.x;
    s_cb[tid] = codebook[tid];
    s_mw1[tid] = mw1[tid];
    if (tid < 16) s_mb1[tid] = mb1[tid];
    if (tid < 48) s_mw2[tid] = mw2[tid];
    if (tid < 3)  s_mb2[tid] = mb2[tid];
    if (tid < 10) { s_rd[tid] = rD[tid]; s_ra[tid] = rA[tid]; s_rr[tid] = rR[tid]; }
    __syncthreads();

    int a = tid >> 4, b = tid & 15;
    float pf[16];
    #pragma unroll
    for (int j = 0; j < 16; ++j) pf[j] = s_cb[a * 16 + j] + s_cb[b * 16 + j];
    float hid[16];
    #pragma unroll
    for (int i = 0; i < 16; ++i) {
        float acc = s_mb1[i];
        #pragma unroll
        for (int j = 0; j < 16; ++j) acc += pf[j] * s_mw1[i * 16 + j];
        hid[i] = acc / (1.0f + __expf(-acc));
    }
    float del[3];
    #pragma unroll
    for (int r = 0; r < 3; ++r) {
        float acc = s_mb2[r];
        #pragma unroll
        for (int i = 0; i < 16; ++i) acc += hid[i] * s_mw2[r * 16 + i];
        del[r] = acc;
    }
    #pragma unroll
    for (int p = 0; p < 10; ++p) {
        float xd = s_rd[p] + del[0];
        float xa = s_ra[p] + del[1];
        float De = (xd > 20.f) ? xd : log1pf(__expf(xd));   // softplus
        float al = (xa > 20.f) ? xa : log1pf(__expf(xa));
        float r0 = s_rr[p] + del[2];
        table[tid * 10 + p] = make_float4(De, al, r0, 0.f);
    }
    if (tid == 0) out_loss[0] = 0.25f * loss[0] * inv_nd;
}

// ---------------------------------------------------------------------------
// K6: per-edge output = table[(at[src]*16 + at[tgt])*10 + pair_idx]
// ---------------------------------------------------------------------------
__global__ void __launch_bounds__(256) k_out(
        const int* __restrict__ src, const int* __restrict__ tgt,
        const int* __restrict__ pidx, const int* __restrict__ atype,
        const float4* __restrict__ table, float2* __restrict__ out, int Ehalf)
{
    int i = blockIdx.x * 256 + threadIdx.x;
    if (i >= Ehalf) return;
    int2 s2 = ((const int2*)src)[i];
    int2 t2 = ((const int2*)tgt)[i];
    int2 p2 = ((const int2*)pidx)[i];
    int i0 = (atype[s2.x] * 16 + atype[t2.x]) * 10 + p2.x;
    int i1 = (atype[s2.y] * 16 + atype[t2.y]) * 10 + p2.y;
    float4 t0 = table[i0];
    float4 t1 = table[i1];
    float2* op = out + (size_t)3 * i;
    op[0] = make_float2(t0.x, t0.y);
    op[1] = make_float2(t0.z, t1.x);
    op[2] = make_float2(t1.y, t1.z);
}

// ---------------------------------------------------------------------------
extern "C" void kernel_launch(void* const* d_in, const int* in_sizes, int n_in,
                              void* d_out, int out_size, void* d_ws, size_t ws_size,
                              hipStream_t stream)
{
    (void)n_in; (void)out_size;
    const int*   elem  = (const int*)d_in[0];
    const int*   eidx  = (const int*)d_in[1];
    const float* dist  = (const float*)d_in[2];
    const int*   pidx  = (const int*)d_in[3];
    const float* embed = (const float*)d_in[4];
    const float* fw1   = (const float*)d_in[5];
    const float* fb1   = (const float*)d_in[6];
    const float* fw2   = (const float*)d_in[7];
    const float* fb2   = (const float*)d_in[8];
    const float* mw1   = (const float*)d_in[9];
    const float* mb1   = (const float*)d_in[10];
    const float* mw2   = (const float*)d_in[11];
    const float* mb2   = (const float*)d_in[12];
    const float* cb    = (const float*)d_in[13];
    const float* rD    = (const float*)d_in[14];
    const float* rA    = (const float*)d_in[15];
    const float* rR    = (const float*)d_in[16];

    int N = in_sizes[0];
    int E = in_sizes[2];
    const int* src = eidx;
    const int* tgt = eidx + E;
    int N4 = N * 4;
    int NB4 = (N4 + 255) / 256;
    if (NB4 > 2048) return;                     // scan2 capacity

    // ---- workspace layout ----
    char* ws = (char*)d_ws;
    size_t cur = 0;
    int*   deg4  = (int*)(ws + cur);  cur += (size_t)N4 * 4;
    float* loss  = (float*)(ws + cur); cur += 4;           // memset with deg4
    size_t clearB = cur;
    int*   offs4 = (int*)(ws + cur);  cur += (size_t)(N4 + 1) * 4;
    int*   bsum  = (int*)(ws + cur);  cur += 2048 * 4;
    int*   atype = (int*)(ws + cur);  cur += (size_t)N * 4;
    cur = (cur + 15) & ~(size_t)15;
    float4* table = (float4*)(ws + cur); cur += 2560 * sizeof(float4);
    if (ws_size < cur) return;

    // scratch inside d_out (dead before k_table/k_out write it):
    float* payload = (float*)d_out;                             // E floats
    unsigned short* packed = (unsigned short*)((char*)d_out + (size_t)E * 4);

    hipMemsetAsync(d_ws, 0, clearB, stream);    // deg4 + loss

    k_rank<<<(E + 255) / 256, 256, 0, stream>>>(src, tgt, elem, deg4, packed, E);
    k_scan1<<<NB4, 256, 0, stream>>>(deg4, offs4, bsum, N4);
    k_scan2<<<1, 256, 0, stream>>>(bsum, NB4);
    k_scan3<<<(N4 + 256) / 256, 256, 0, stream>>>(offs4, bsum, N4, E);
    k_scatter<<<(E + 255) / 256, 256, 0, stream>>>(src, dist, packed, offs4,
                                                   payload, E);
    k_gather<<<(N + 31) / 32, 256, 0, stream>>>(elem, embed, cb, fw1, fb1,
                                                fw2, fb2, offs4, payload,
                                                atype, loss, N);
    float* outl = (float*)d_out + (size_t)3 * E;
    k_table<<<1, 256, 0, stream>>>(cb, mw1, mb1, mw2, mb2, rD, rA, rR,
                                   loss, table, outl,
                                   1.0f / (float)((size_t)N * 16));
    k_out<<<(E / 2 + 255) / 256, 256, 0, stream>>>(src, tgt, pidx, atype, table,
                                                   (float2*)d_out, E / 2);
}

// Round 9
// 365.253 us; speedup vs baseline: 6.1039x; 1.0859x over previous
//
#include <hip/hip_runtime.h>
#include <stdint.h>

#define A2B   1.8897259886f
#define R_MIN (0.5f * A2B)
#define R_MAX (4.0f * A2B)

// ---------------------------------------------------------------------------
// K1: per-edge rank within (src, elem[tgt]) bin -- one int atomic per edge
// ---------------------------------------------------------------------------
__global__ void __launch_bounds__(256) k_rank(
        const int* __restrict__ src, const int* __restrict__ tgt,
        const int* __restrict__ elem, int* __restrict__ deg4,
        unsigned short* __restrict__ packed, int E)
{
    int e = blockIdx.x * 256 + threadIdx.x;
    if (e >= E) return;
    int s = src[e];
    int q = elem[tgt[e]];
    int r = atomicAdd(deg4 + s * 4 + q, 1);        // rank within (node,q) bin
    packed[e] = (unsigned short)(r | (q << 12));   // r < 4096 (mean bin = 8)
}

// ---------------------------------------------------------------------------
// K2a/b/c: exclusive scan of deg4[N4] -> offs4[N4+1]
//          scan1: 1024 elems/block (4/thread) so scan2 only does 2 chunks
// ---------------------------------------------------------------------------
__global__ void __launch_bounds__(256) k_scan1(
        const int* __restrict__ deg, int* __restrict__ offs,
        int* __restrict__ bsum, int N4)
{
    __shared__ int sd[256];
    int t = threadIdx.x;
    int base = blockIdx.x * 1024 + t * 4;
    int v0, v1, v2, v3;
    if (base + 3 < N4) {
        int4 vv = *(const int4*)(deg + base);
        v0 = vv.x; v1 = vv.y; v2 = vv.z; v3 = vv.w;
    } else {
        v0 = (base + 0 < N4) ? deg[base + 0] : 0;
        v1 = (base + 1 < N4) ? deg[base + 1] : 0;
        v2 = (base + 2 < N4) ? deg[base + 2] : 0;
        v3 = (base + 3 < N4) ? deg[base + 3] : 0;
    }
    int tot = v0 + v1 + v2 + v3;
    sd[t] = tot; __syncthreads();
    #pragma unroll
    for (int o = 1; o < 256; o <<= 1) {
        int x = (t >= o) ? sd[t - o] : 0;
        __syncthreads();
        sd[t] += x;
        __syncthreads();
    }
    int ex = sd[t] - tot;                           // exclusive thread base
    if (base + 0 < N4) offs[base + 0] = ex;
    if (base + 1 < N4) offs[base + 1] = ex + v0;
    if (base + 2 < N4) offs[base + 2] = ex + v0 + v1;
    if (base + 3 < N4) offs[base + 3] = ex + v0 + v1 + v2;
    if (t == 255) bsum[blockIdx.x] = sd[255];       // block total
}

// chunked single-block scan: handles NB up to 2048 block-sums
__global__ void __launch_bounds__(256) k_scan2(int* __restrict__ bsum, int NB)
{
    __shared__ int sd[256];
    __shared__ int carry;
    int t = threadIdx.x;
    if (t == 0) carry = 0;
    __syncthreads();
    for (int base = 0; base < NB; base += 256) {
        int i = base + t;
        int v = (i < NB) ? bsum[i] : 0;
        sd[t] = v; __syncthreads();
        #pragma unroll
        for (int o = 1; o < 256; o <<= 1) {
            int x = (t >= o) ? sd[t - o] : 0;
            __syncthreads();
            sd[t] += x;
            __syncthreads();
        }
        int c = carry;                              // uniform read
        if (i < NB) bsum[i] = c + sd[t] - v;        // exclusive block base
        __syncthreads();
        if (t == 255) carry = c + sd[255];
        __syncthreads();
    }
}

__global__ void __launch_bounds__(256) k_scan3(
        int* __restrict__ offs, const int* __restrict__ bsum, int N4, int E)
{
    int i = blockIdx.x * 256 + threadIdx.x;
    if (i < N4) offs[i] += bsum[i >> 10];
    else if (i == N4) offs[N4] = E;
}

// ---------------------------------------------------------------------------
// K3: scatter 4B payload (dist) to (node,q)-binned CSR slot [lives in d_out]
// ---------------------------------------------------------------------------
__global__ void __launch_bounds__(256) k_scatter(
        const int* __restrict__ src, const float* __restrict__ dist,
        const unsigned short* __restrict__ packed, const int* __restrict__ offs4,
        float* __restrict__ payload, int E)
{
    int e = blockIdx.x * 256 + threadIdx.x;
    if (e >= E) return;
    unsigned p = packed[e];
    int q = (int)(p >> 12);
    int pos = offs4[src[e] * 4 + q] + (int)(p & 0xFFF);
    payload[pos] = dist[e];
}

// ---------------------------------------------------------------------------
// K4: gather, 8 lanes/node, (node,q)-binned edges, 2 edges per lane per pass.
//     Layer 1 per edge; layer 2 applied once per bin (affine hoist, exact).
//     Pairing halves the dominant cost (broadcast ds_read_b128 of fw1t).
//     silu via native v_rcp_f32 (removes 16 IEEE-div sequences per edge).
//     Register note (r4-r7): NO min-waves cap -- caps forced spills.
// ---------------------------------------------------------------------------
__global__ void __launch_bounds__(256) k_gather(
        const int* __restrict__ elem, const float* __restrict__ embed,
        const float* __restrict__ codebook,
        const float* __restrict__ fw1, const float* __restrict__ fb1,
        const float* __restrict__ fw2, const float* __restrict__ fb2,
        const int* __restrict__ offs4, const float* __restrict__ payload,
        int* __restrict__ atype, float* __restrict__ loss, int N)
{
    __shared__ float4 s_fw1t[64];   // [k][i2/4]: fw1t[k][i2] = fw1[i2][k]
    __shared__ float4 s_fw2v[64];   // [j][i2/4]
    __shared__ float s_cb[256];
    __shared__ float s_fb1[16], s_fb2[16], s_emb[64], s_cbn[16];
    __shared__ float s_red[4];
    int t = threadIdx.x;
    {
        float* f1 = (float*)s_fw1t;
        f1[(t & 15) * 16 + (t >> 4)] = fw1[t];     // transpose on stage
        float* f2 = (float*)s_fw2v;
        f2[t] = fw2[t];
        s_cb[t] = codebook[t];
    }
    if (t < 16) { s_fb1[t] = fb1[t]; s_fb2[t] = fb2[t]; }
    if (t < 64) s_emb[t] = embed[t];
    __syncthreads();
    if (t < 16) {
        float s = 0.f;
        #pragma unroll
        for (int j = 0; j < 16; ++j) { float c = s_cb[t * 16 + j]; s += c * c; }
        s_cbn[t] = s;
    }
    __syncthreads();

    int node = blockIdx.x * 32 + (t >> 3);   // 8 lanes per node
    int sub  = t & 7;
    float lp = 0.0f;
    float acc[16];
    #pragma unroll
    for (int j = 0; j < 16; ++j) acc[j] = 0.f;

    if (node < N) {
        const float invw   = 16.0f / (R_MAX - R_MIN);            // 1/width
        const float u0base = R_MIN * invw;                       // offset
        const float kstep  = 16.0f / 15.0f;                      // step*invw
        #pragma clang loop unroll(disable)
        for (int qq = 0; qq < 4; ++qq) {
            int b0 = offs4[node * 4 + qq], b1 = offs4[node * 4 + qq + 1];
            if (b0 == b1) continue;
            float G[16];
            #pragma unroll
            for (int j = 0; j < 16; ++j) G[j] = 0.f;
            for (int i = b0 + sub; i < b1; i += 16) {
                int ii = i + 8;
                bool has2 = (ii < b1);
                float d0 = payload[i];
                float d1 = has2 ? payload[ii] : d0;
                float ua = d0 * invw - u0base;
                float ub = d1 * invw - u0base;
                float g0[16], g1[16];
                #pragma unroll
                for (int i2 = 0; i2 < 16; ++i2) { g0[i2] = s_fb1[i2]; g1[i2] = s_fb1[i2]; }
                #pragma clang loop unroll(disable)
                for (int k = 0; k < 16; ++k) {
                    float r0 = __expf(-0.5f * ua * ua);
                    float r1 = __expf(-0.5f * ub * ub);
                    float4 w0 = s_fw1t[k*4+0], w1 = s_fw1t[k*4+1];
                    float4 w2 = s_fw1t[k*4+2], w3 = s_fw1t[k*4+3];
                    g0[0]+=r0*w0.x;  g0[1]+=r0*w0.y;  g0[2]+=r0*w0.z;  g0[3]+=r0*w0.w;
                    g0[4]+=r0*w1.x;  g0[5]+=r0*w1.y;  g0[6]+=r0*w1.z;  g0[7]+=r0*w1.w;
                    g0[8]+=r0*w2.x;  g0[9]+=r0*w2.y;  g0[10]+=r0*w2.z; g0[11]+=r0*w2.w;
                    g0[12]+=r0*w3.x; g0[13]+=r0*w3.y; g0[14]+=r0*w3.z; g0[15]+=r0*w3.w;
                    g1[0]+=r1*w0.x;  g1[1]+=r1*w0.y;  g1[2]+=r1*w0.z;  g1[3]+=r1*w0.w;
                    g1[4]+=r1*w1.x;  g1[5]+=r1*w1.y;  g1[6]+=r1*w1.z;  g1[7]+=r1*w1.w;
                    g1[8]+=r1*w2.x;  g1[9]+=r1*w2.y;  g1[10]+=r1*w2.z; g1[11]+=r1*w2.w;
                    g1[12]+=r1*w3.x; g1[13]+=r1*w3.y; g1[14]+=r1*w3.z; g1[15]+=r1*w3.w;
                    ua -= kstep; ub -= kstep;
                }
                #pragma unroll
                for (int i2 = 0; i2 < 16; ++i2) {
                    float a = g0[i2];
                    G[i2] += a * __builtin_amdgcn_rcpf(1.0f + __expf(-a));
                }
                if (has2) {
                    #pragma unroll
                    for (int i2 = 0; i2 < 16; ++i2) {
                        float a = g1[i2];
                        G[i2] += a * __builtin_amdgcn_rcpf(1.0f + __expf(-a));
                    }
                }
            }
            // layer 2 once per bin on per-lane partial G (exact: L2 affine)
            const float* er = s_emb + qq * 16;
            #pragma clang loop unroll_count(4)
            for (int j = 0; j < 16; ++j) {
                float4 f0 = s_fw2v[j*4+0], f1 = s_fw2v[j*4+1];
                float4 f2 = s_fw2v[j*4+2], f3 = s_fw2v[j*4+3];
                float w = G[0]*f0.x  + G[1]*f0.y  + G[2]*f0.z  + G[3]*f0.w
                        + G[4]*f1.x  + G[5]*f1.y  + G[6]*f1.z  + G[7]*f1.w
                        + G[8]*f2.x  + G[9]*f2.y  + G[10]*f2.z + G[11]*f2.w
                        + G[12]*f3.x + G[13]*f3.y + G[14]*f3.z + G[15]*f3.w;
                acc[j] += w * er[j];
            }
            if (sub == 0) {
                float nb = (float)(b1 - b0);
                #pragma unroll
                for (int j = 0; j < 16; ++j)
                    acc[j] += nb * s_fb2[j] * er[j];       // count term
            }
        }
        // 8-lane group reduction
        #pragma unroll
        for (int m = 1; m <= 4; m <<= 1) {
            #pragma unroll
            for (int j = 0; j < 16; ++j)
                acc[j] += __shfl_xor(acc[j], m, 64);
        }
        int qn = elem[node];
        float h[16], hh = 0.f;
        #pragma unroll
        for (int j = 0; j < 16; ++j) {
            h[j] = acc[j] + s_emb[qn * 16 + j];
            hh += h[j] * h[j];
        }
        float best = __builtin_inff(); int bi = 0;
        #pragma unroll
        for (int c = 0; c < 4; ++c) {
            int code = qn * 4 + c;
            float dot = 0.f;
            #pragma unroll
            for (int j = 0; j < 16; ++j) dot += h[j] * s_cb[code * 16 + j];
            float d2 = hh - 2.0f * dot + s_cbn[code];
            if (d2 < best) { best = d2; bi = code; }
        }
        if (sub == 0) {
            atype[node] = bi;
            #pragma unroll
            for (int j = 0; j < 16; ++j) {
                float df = h[j] - s_cb[bi * 16 + j];
                lp += df * df;
            }
        }
    }
    // block reduction of loss partials
    #pragma unroll
    for (int o = 32; o > 0; o >>= 1) lp += __shfl_down(lp, o, 64);
    int wid = t >> 6;
    if ((t & 63) == 0) s_red[wid] = lp;
    __syncthreads();
    if (t == 0) atomicAdd(loss, s_red[0] + s_red[1] + s_red[2] + s_red[3]);
}

// ---------------------------------------------------------------------------
// K5: build the 2560-entry (combo x pair) output table; finalize vq_loss
// ---------------------------------------------------------------------------
__global__ void __launch_bounds__(256) k_table(
        const float* __restrict__ codebook,
        const float* __restrict__ mw1, const float* __restrict__ mb1,
        const float* __restrict__ mw2, const float* __restrict__ mb2,
        const float* __restrict__ rD, const float* __restrict__ rA,
        const float* __restrict__ rR,
        const float* __restrict__ loss, float4* __restrict__ table,
        float* __restrict__ out_loss, float inv_nd)
{
    __shared__ float s_cb[256], s_mw1[256], s_mb1[16], s_mw2[48], s_mb2[3];
    __shared__ float s_rd[10], s_ra[10], s_rr[10];
    int tid = threadIdx.x;
    s_cb[tid] = codebook[tid];
    s_mw1[tid] = mw1[tid];
    if (tid < 16) s_mb1[tid] = mb1[tid];
    if (tid < 48) s_mw2[tid] = mw2[tid];
    if (tid < 3)  s_mb2[tid] = mb2[tid];
    if (tid < 10) { s_rd[tid] = rD[tid]; s_ra[tid] = rA[tid]; s_rr[tid] = rR[tid]; }
    __syncthreads();

    int a = tid >> 4, b = tid & 15;
    float pf[16];
    #pragma unroll
    for (int j = 0; j < 16; ++j) pf[j] = s_cb[a * 16 + j] + s_cb[b * 16 + j];
    float hid[16];
    #pragma unroll
    for (int i = 0; i < 16; ++i) {
        float acc = s_mb1[i];
        #pragma unroll
        for (int j = 0; j < 16; ++j) acc += pf[j] * s_mw1[i * 16 + j];
        hid[i] = acc / (1.0f + __expf(-acc));
    }
    float del[3];
    #pragma unroll
    for (int r = 0; r < 3; ++r) {
        float acc = s_mb2[r];
        #pragma unroll
        for (int i = 0; i < 16; ++i) acc += hid[i] * s_mw2[r * 16 + i];
        del[r] = acc;
    }
    #pragma unroll
    for (int p = 0; p < 10; ++p) {
        float xd = s_rd[p] + del[0];
        float xa = s_ra[p] + del[1];
        float De = (xd > 20.f) ? xd : log1pf(__expf(xd));   // softplus
        float al = (xa > 20.f) ? xa : log1pf(__expf(xa));
        float r0 = s_rr[p] + del[2];
        table[tid * 10 + p] = make_float4(De, al, r0, 0.f);
    }
    if (tid == 0) out_loss[0] = 0.25f * loss[0] * inv_nd;
}

// ---------------------------------------------------------------------------
// K6: per-edge output = table[(at[src]*16 + at[tgt])*10 + pair_idx]
// ---------------------------------------------------------------------------
__global__ void __launch_bounds__(256) k_out(
        const int* __restrict__ src, const int* __restrict__ tgt,
        const int* __restrict__ pidx, const int* __restrict__ atype,
        const float4* __restrict__ table, float2* __restrict__ out, int Ehalf)
{
    int i = blockIdx.x * 256 + threadIdx.x;
    if (i >= Ehalf) return;
    int2 s2 = ((const int2*)src)[i];
    int2 t2 = ((const int2*)tgt)[i];
    int2 p2 = ((const int2*)pidx)[i];
    int i0 = (atype[s2.x] * 16 + atype[t2.x]) * 10 + p2.x;
    int i1 = (atype[s2.y] * 16 + atype[t2.y]) * 10 + p2.y;
    float4 t0 = table[i0];
    float4 t1 = table[i1];
    float2* op = out + (size_t)3 * i;
    op[0] = make_float2(t0.x, t0.y);
    op[1] = make_float2(t0.z, t1.x);
    op[2] = make_float2(t1.y, t1.z);
}

// ---------------------------------------------------------------------------
extern "C" void kernel_launch(void* const* d_in, const int* in_sizes, int n_in,
                              void* d_out, int out_size, void* d_ws, size_t ws_size,
                              hipStream_t stream)
{
    (void)n_in; (void)out_size;
    const int*   elem  = (const int*)d_in[0];
    const int*   eidx  = (const int*)d_in[1];
    const float* dist  = (const float*)d_in[2];
    const int*   pidx  = (const int*)d_in[3];
    const float* embed = (const float*)d_in[4];
    const float* fw1   = (const float*)d_in[5];
    const float* fb1   = (const float*)d_in[6];
    const float* fw2   = (const float*)d_in[7];
    const float* fb2   = (const float*)d_in[8];
    const float* mw1   = (const float*)d_in[9];
    const float* mb1   = (const float*)d_in[10];
    const float* mw2   = (const float*)d_in[11];
    const float* mb2   = (const float*)d_in[12];
    const float* cb    = (const float*)d_in[13];
    const float* rD    = (const float*)d_in[14];
    const float* rA    = (const float*)d_in[15];
    const float* rR    = (const float*)d_in[16];

    int N = in_sizes[0];
    int E = in_sizes[2];
    const int* src = eidx;
    const int* tgt = eidx + E;
    int N4 = N * 4;
    int NB4 = (N4 + 1023) / 1024;
    if (NB4 > 2048) return;                     // scan2 capacity

    // ---- workspace layout ----
    char* ws = (char*)d_ws;
    size_t cur = 0;
    int*   deg4  = (int*)(ws + cur);  cur += (size_t)N4 * 4;
    float* loss  = (float*)(ws + cur); cur += 4;           // memset with deg4
    size_t clearB = cur;
    int*   offs4 = (int*)(ws + cur);  cur += (size_t)(N4 + 1) * 4;
    int*   bsum  = (int*)(ws + cur);  cur += 2048 * 4;
    int*   atype = (int*)(ws + cur);  cur += (size_t)N * 4;
    cur = (cur + 15) & ~(size_t)15;
    float4* table = (float4*)(ws + cur); cur += 2560 * sizeof(float4);
    if (ws_size < cur) return;

    // scratch inside d_out (dead before k_table/k_out write it):
    float* payload = (float*)d_out;                             // E floats
    unsigned short* packed = (unsigned short*)((char*)d_out + (size_t)E * 4);

    hipMemsetAsync(d_ws, 0, clearB, stream);    // deg4 + loss

    k_rank<<<(E + 255) / 256, 256, 0, stream>>>(src, tgt, elem, deg4, packed, E);
    k_scan1<<<NB4, 256, 0, stream>>>(deg4, offs4, bsum, N4);
    k_scan2<<<1, 256, 0, stream>>>(bsum, NB4);
    k_scan3<<<(N4 + 256) / 256, 256, 0, stream>>>(offs4, bsum, N4, E);
    k_scatter<<<(E + 255) / 256, 256, 0, stream>>>(src, dist, packed, offs4,
                                                   payload, E);
    k_gather<<<(N + 31) / 32, 256, 0, stream>>>(elem, embed, cb, fw1, fb1,
                                                fw2, fb2, offs4, payload,
                                                atype, loss, N);
    float* outl = (float*)d_out + (size_t)3 * E;
    k_table<<<1, 256, 0, stream>>>(cb, mw1, mb1, mw2, mb2, rD, rA, rR,
                                   loss, table, outl,
                                   1.0f / (float)((size_t)N * 16));
    k_out<<<(E / 2 + 255) / 256, 256, 0, stream>>>(src, tgt, pidx, atype, table,
                                                   (float2*)d_out, E / 2);
}

// Round 10
// 302.420 us; speedup vs baseline: 7.3721x; 1.2078x over previous
//
#include <hip/hip_runtime.h>
#include <stdint.h>

#define A2B   1.8897259886f
#define R_MIN (0.5f * A2B)
#define R_MAX (4.0f * A2B)

#define EPB 2048      // edges per k_bucket block

// ---------------------------------------------------------------------------
// K1: bucket multisplit pass A. Buckets = node>>SHIFT (<=256 buckets).
//     Per block: LDS histogram -> 1 global atomic per nonempty bucket ->
//     LDS-cursor placement of (d, localBin) into per-bucket regions.
//     Replaces 3.2M global atomics (k_rank) with ~306k.
// ---------------------------------------------------------------------------
__global__ void __launch_bounds__(256) k_bucket(
        const int* __restrict__ src, const int* __restrict__ tgt,
        const int* __restrict__ elem, const float* __restrict__ dist,
        int* __restrict__ gCursor, float* __restrict__ dBuf,
        unsigned short* __restrict__ kBuf, int CAP, int SHIFT, int E)
{
    __shared__ int cnt[256], base_[256];
    int t = threadIdx.x;
    cnt[t] = 0;
    __syncthreads();
    int e0 = blockIdx.x * EPB;
    int eEnd = (e0 + EPB < E) ? e0 + EPB : E;

    float dv[8]; int bv[8]; unsigned short kv[8];
    #pragma unroll
    for (int j = 0; j < 8; ++j) {
        int e = e0 + t + j * 256;
        if (e < eEnd) {
            int s = src[e];
            int q = elem[tgt[e]];
            dv[j] = dist[e];
            int b = s >> SHIFT;
            bv[j] = b;
            kv[j] = (unsigned short)(((s - (b << SHIFT)) << 2) | q);
            atomicAdd(&cnt[b], 1);
        }
    }
    __syncthreads();
    if (cnt[t] > 0) base_[t] = atomicAdd(&gCursor[t], cnt[t]);
    __syncthreads();
    cnt[t] = 0;                       // reuse as block-local cursor
    __syncthreads();
    #pragma unroll
    for (int j = 0; j < 8; ++j) {
        int e = e0 + t + j * 256;
        if (e < eEnd) {
            int b = bv[j];
            int pos = base_[b] + atomicAdd(&cnt[b], 1);
            if (pos < CAP) {          // statistically never (CAP = mean+10sd)
                size_t idx = (size_t)b * CAP + pos;
                dBuf[idx] = dv[j];
                kBuf[idx] = kv[j];
            }
        }
    }
}

// ---------------------------------------------------------------------------
// K2: tiny scan of bucket counts -> bucket bases; also offs4[N4] = E
// ---------------------------------------------------------------------------
__global__ void __launch_bounds__(256) k_bscan(
        const int* __restrict__ gCursor, int* __restrict__ bucketBase,
        int* __restrict__ offs4, int NBUK, int N4, int E)
{
    __shared__ int sd[256];
    int t = threadIdx.x;
    int v = (t < NBUK) ? gCursor[t] : 0;
    sd[t] = v; __syncthreads();
    #pragma unroll
    for (int o = 1; o < 256; o <<= 1) {
        int x = (t >= o) ? sd[t - o] : 0;
        __syncthreads();
        sd[t] += x;
        __syncthreads();
    }
    bucketBase[t] = sd[t] - v;        // exclusive
    if (t == 0) offs4[N4] = E;
}

// ---------------------------------------------------------------------------
// K3: pass B. One block per bucket: LDS bin-count (<=2048 bins) -> in-LDS
//     exclusive scan -> write offs4 -> LDS-cursor placement of payload.
//     Zero global atomics; replaces k_scan1/2/3 + k_scatter.
// ---------------------------------------------------------------------------
__global__ void __launch_bounds__(256) k_bin(
        const float* __restrict__ dBuf, const unsigned short* __restrict__ kBuf,
        const int* __restrict__ gCursor, const int* __restrict__ bucketBase,
        int* __restrict__ offs4, float* __restrict__ payload,
        int CAP, int SHIFT, int N)
{
    __shared__ int lcnt[2048];
    __shared__ int sd[256];
    int t = threadIdx.x, b = blockIdx.x;
    int n0 = b << SHIFT;
    int n1 = n0 + (1 << SHIFT); if (n1 > N) n1 = N;
    int m  = (n1 - n0) * 4;
    int cntE = gCursor[b]; if (cntE > CAP) cntE = CAP;
    int base = bucketBase[b];
    for (int i = t; i < m; i += 256) lcnt[i] = 0;
    __syncthreads();
    const float* dB = dBuf + (size_t)b * CAP;
    const unsigned short* kB = kBuf + (size_t)b * CAP;
    for (int i = t; i < cntE; i += 256)
        atomicAdd(&lcnt[kB[i]], 1);
    __syncthreads();
    // exclusive scan over m bins, 8 per thread, in place
    int v[8]; int tsum = 0; int b8 = t * 8;
    #pragma unroll
    for (int j = 0; j < 8; ++j) { v[j] = (b8 + j < m) ? lcnt[b8 + j] : 0; tsum += v[j]; }
    sd[t] = tsum; __syncthreads();
    #pragma unroll
    for (int o = 1; o < 256; o <<= 1) {
        int x = (t >= o) ? sd[t - o] : 0;
        __syncthreads();
        sd[t] += x;
        __syncthreads();
    }
    int run = sd[t] - tsum;
    #pragma unroll
    for (int j = 0; j < 8; ++j) {
        if (b8 + j < m) {
            int c = v[j];
            lcnt[b8 + j] = run;                      // cursor init
            offs4[n0 * 4 + b8 + j] = base + run;     // global CSR offsets
            run += c;
        }
    }
    __syncthreads();
    for (int i = t; i < cntE; i += 256) {
        int pos = atomicAdd(&lcnt[kB[i]], 1);
        payload[base + pos] = dB[i];
    }
}

// ---------------------------------------------------------------------------
// K4: gather -- UNCHANGED from round 9 (141us, VALUBusy 75%).
//     8 lanes/node, (node,q)-binned edges, 2 edges/lane/pass, affine L2 hoist,
//     rcp-silu. Register note (r4-r7): NO min-waves cap (caps forced spills).
// ---------------------------------------------------------------------------
__global__ void __launch_bounds__(256) k_gather(
        const int* __restrict__ elem, const float* __restrict__ embed,
        const float* __restrict__ codebook,
        const float* __restrict__ fw1, const float* __restrict__ fb1,
        const float* __restrict__ fw2, const float* __restrict__ fb2,
        const int* __restrict__ offs4, const float* __restrict__ payload,
        int* __restrict__ atype, float* __restrict__ loss, int N)
{
    __shared__ float4 s_fw1t[64];   // [k][i2/4]: fw1t[k][i2] = fw1[i2][k]
    __shared__ float4 s_fw2v[64];   // [j][i2/4]
    __shared__ float s_cb[256];
    __shared__ float s_fb1[16], s_fb2[16], s_emb[64], s_cbn[16];
    __shared__ float s_red[4];
    int t = threadIdx.x;
    {
        float* f1 = (float*)s_fw1t;
        f1[(t & 15) * 16 + (t >> 4)] = fw1[t];     // transpose on stage
        float* f2 = (float*)s_fw2v;
        f2[t] = fw2[t];
        s_cb[t] = codebook[t];
    }
    if (t < 16) { s_fb1[t] = fb1[t]; s_fb2[t] = fb2[t]; }
    if (t < 64) s_emb[t] = embed[t];
    __syncthreads();
    if (t < 16) {
        float s = 0.f;
        #pragma unroll
        for (int j = 0; j < 16; ++j) { float c = s_cb[t * 16 + j]; s += c * c; }
        s_cbn[t] = s;
    }
    __syncthreads();

    int node = blockIdx.x * 32 + (t >> 3);   // 8 lanes per node
    int sub  = t & 7;
    float lp = 0.0f;
    float acc[16];
    #pragma unroll
    for (int j = 0; j < 16; ++j) acc[j] = 0.f;

    if (node < N) {
        const float invw   = 16.0f / (R_MAX - R_MIN);            // 1/width
        const float u0base = R_MIN * invw;                       // offset
        const float kstep  = 16.0f / 15.0f;                      // step*invw
        #pragma clang loop unroll(disable)
        for (int qq = 0; qq < 4; ++qq) {
            int b0 = offs4[node * 4 + qq], b1 = offs4[node * 4 + qq + 1];
            if (b0 == b1) continue;
            float G[16];
            #pragma unroll
            for (int j = 0; j < 16; ++j) G[j] = 0.f;
            for (int i = b0 + sub; i < b1; i += 16) {
                int ii = i + 8;
                bool has2 = (ii < b1);
                float d0 = payload[i];
                float d1 = has2 ? payload[ii] : d0;
                float ua = d0 * invw - u0base;
                float ub = d1 * invw - u0base;
                float g0[16], g1[16];
                #pragma unroll
                for (int i2 = 0; i2 < 16; ++i2) { g0[i2] = s_fb1[i2]; g1[i2] = s_fb1[i2]; }
                #pragma clang loop unroll(disable)
                for (int k = 0; k < 16; ++k) {
                    float r0 = __expf(-0.5f * ua * ua);
                    float r1 = __expf(-0.5f * ub * ub);
                    float4 w0 = s_fw1t[k*4+0], w1 = s_fw1t[k*4+1];
                    float4 w2 = s_fw1t[k*4+2], w3 = s_fw1t[k*4+3];
                    g0[0]+=r0*w0.x;  g0[1]+=r0*w0.y;  g0[2]+=r0*w0.z;  g0[3]+=r0*w0.w;
                    g0[4]+=r0*w1.x;  g0[5]+=r0*w1.y;  g0[6]+=r0*w1.z;  g0[7]+=r0*w1.w;
                    g0[8]+=r0*w2.x;  g0[9]+=r0*w2.y;  g0[10]+=r0*w2.z; g0[11]+=r0*w2.w;
                    g0[12]+=r0*w3.x; g0[13]+=r0*w3.y; g0[14]+=r0*w3.z; g0[15]+=r0*w3.w;
                    g1[0]+=r1*w0.x;  g1[1]+=r1*w0.y;  g1[2]+=r1*w0.z;  g1[3]+=r1*w0.w;
                    g1[4]+=r1*w1.x;  g1[5]+=r1*w1.y;  g1[6]+=r1*w1.z;  g1[7]+=r1*w1.w;
                    g1[8]+=r1*w2.x;  g1[9]+=r1*w2.y;  g1[10]+=r1*w2.z; g1[11]+=r1*w2.w;
                    g1[12]+=r1*w3.x; g1[13]+=r1*w3.y; g1[14]+=r1*w3.z; g1[15]+=r1*w3.w;
                    ua -= kstep; ub -= kstep;
                }
                #pragma unroll
                for (int i2 = 0; i2 < 16; ++i2) {
                    float a = g0[i2];
                    G[i2] += a * __builtin_amdgcn_rcpf(1.0f + __expf(-a));
                }
                if (has2) {
                    #pragma unroll
                    for (int i2 = 0; i2 < 16; ++i2) {
                        float a = g1[i2];
                        G[i2] += a * __builtin_amdgcn_rcpf(1.0f + __expf(-a));
                    }
                }
            }
            // layer 2 once per bin on per-lane partial G (exact: L2 affine)
            const float* er = s_emb + qq * 16;
            #pragma clang loop unroll_count(4)
            for (int j = 0; j < 16; ++j) {
                float4 f0 = s_fw2v[j*4+0], f1 = s_fw2v[j*4+1];
                float4 f2 = s_fw2v[j*4+2], f3 = s_fw2v[j*4+3];
                float w = G[0]*f0.x  + G[1]*f0.y  + G[2]*f0.z  + G[3]*f0.w
                        + G[4]*f1.x  + G[5]*f1.y  + G[6]*f1.z  + G[7]*f1.w
                        + G[8]*f2.x  + G[9]*f2.y  + G[10]*f2.z + G[11]*f2.w
                        + G[12]*f3.x + G[13]*f3.y + G[14]*f3.z + G[15]*f3.w;
                acc[j] += w * er[j];
            }
            if (sub == 0) {
                float nb = (float)(b1 - b0);
                #pragma unroll
                for (int j = 0; j < 16; ++j)
                    acc[j] += nb * s_fb2[j] * er[j];       // count term
            }
        }
        // 8-lane group reduction
        #pragma unroll
        for (int m = 1; m <= 4; m <<= 1) {
            #pragma unroll
            for (int j = 0; j < 16; ++j)
                acc[j] += __shfl_xor(acc[j], m, 64);
        }
        int qn = elem[node];
        float h[16], hh = 0.f;
        #pragma unroll
        for (int j = 0; j < 16; ++j) {
            h[j] = acc[j] + s_emb[qn * 16 + j];
            hh += h[j] * h[j];
        }
        float best = __builtin_inff(); int bi = 0;
        #pragma unroll
        for (int c = 0; c < 4; ++c) {
            int code = qn * 4 + c;
            float dot = 0.f;
            #pragma unroll
            for (int j = 0; j < 16; ++j) dot += h[j] * s_cb[code * 16 + j];
            float d2 = hh - 2.0f * dot + s_cbn[code];
            if (d2 < best) { best = d2; bi = code; }
        }
        if (sub == 0) {
            atype[node] = bi;
            #pragma unroll
            for (int j = 0; j < 16; ++j) {
                float df = h[j] - s_cb[bi * 16 + j];
                lp += df * df;
            }
        }
    }
    // block reduction of loss partials
    #pragma unroll
    for (int o = 32; o > 0; o >>= 1) lp += __shfl_down(lp, o, 64);
    int wid = t >> 6;
    if ((t & 63) == 0) s_red[wid] = lp;
    __syncthreads();
    if (t == 0) atomicAdd(loss, s_red[0] + s_red[1] + s_red[2] + s_red[3]);
}

// ---------------------------------------------------------------------------
// K5: build the 2560-entry (combo x pair) output table; finalize vq_loss
// ---------------------------------------------------------------------------
__global__ void __launch_bounds__(256) k_table(
        const float* __restrict__ codebook,
        const float* __restrict__ mw1, const float* __restrict__ mb1,
        const float* __restrict__ mw2, const float* __restrict__ mb2,
        const float* __restrict__ rD, const float* __restrict__ rA,
        const float* __restrict__ rR,
        const float* __restrict__ loss, float4* __restrict__ table,
        float* __restrict__ out_loss, float inv_nd)
{
    __shared__ float s_cb[256], s_mw1[256], s_mb1[16], s_mw2[48], s_mb2[3];
    __shared__ float s_rd[10], s_ra[10], s_rr[10];
    int tid = threadIdx.x;
    s_cb[tid] = codebook[tid];
    s_mw1[tid] = mw1[tid];
    if (tid < 16) s_mb1[tid] = mb1[tid];
    if (tid < 48) s_mw2[tid] = mw2[tid];
    if (tid < 3)  s_mb2[tid] = mb2[tid];
    if (tid < 10) { s_rd[tid] = rD[tid]; s_ra[tid] = rA[tid]; s_rr[tid] = rR[tid]; }
    __syncthreads();

    int a = tid >> 4, b = tid & 15;
    float pf[16];
    #pragma unroll
    for (int j = 0; j < 16; ++j) pf[j] = s_cb[a * 16 + j] + s_cb[b * 16 + j];
    float hid[16];
    #pragma unroll
    for (int i = 0; i < 16; ++i) {
        float acc = s_mb1[i];
        #pragma unroll
        for (int j = 0; j < 16; ++j) acc += pf[j] * s_mw1[i * 16 + j];
        hid[i] = acc / (1.0f + __expf(-acc));
    }
    float del[3];
    #pragma unroll
    for (int r = 0; r < 3; ++r) {
        float acc = s_mb2[r];
        #pragma unroll
        for (int i = 0; i < 16; ++i) acc += hid[i] * s_mw2[r * 16 + i];
        del[r] = acc;
    }
    #pragma unroll
    for (int p = 0; p < 10; ++p) {
        float xd = s_rd[p] + del[0];
        float xa = s_ra[p] + del[1];
        float De = (xd > 20.f) ? xd : log1pf(__expf(xd));   // softplus
        float al = (xa > 20.f) ? xa : log1pf(__expf(xa));
        float r0 = s_rr[p] + del[2];
        table[tid * 10 + p] = make_float4(De, al, r0, 0.f);
    }
    if (tid == 0) out_loss[0] = 0.25f * loss[0] * inv_nd;
}

// ---------------------------------------------------------------------------
// K6: per-edge output = table[(at[src]*16 + at[tgt])*10 + pair_idx]
// ---------------------------------------------------------------------------
__global__ void __launch_bounds__(256) k_out(
        const int* __restrict__ src, const int* __restrict__ tgt,
        const int* __restrict__ pidx, const int* __restrict__ atype,
        const float4* __restrict__ table, float2* __restrict__ out, int Ehalf)
{
    int i = blockIdx.x * 256 + threadIdx.x;
    if (i >= Ehalf) return;
    int2 s2 = ((const int2*)src)[i];
    int2 t2 = ((const int2*)tgt)[i];
    int2 p2 = ((const int2*)pidx)[i];
    int i0 = (atype[s2.x] * 16 + atype[t2.x]) * 10 + p2.x;
    int i1 = (atype[s2.y] * 16 + atype[t2.y]) * 10 + p2.y;
    float4 t0 = table[i0];
    float4 t1 = table[i1];
    float2* op = out + (size_t)3 * i;
    op[0] = make_float2(t0.x, t0.y);
    op[1] = make_float2(t0.z, t1.x);
    op[2] = make_float2(t1.y, t1.z);
}

// ---------------------------------------------------------------------------
extern "C" void kernel_launch(void* const* d_in, const int* in_sizes, int n_in,
                              void* d_out, int out_size, void* d_ws, size_t ws_size,
                              hipStream_t stream)
{
    (void)n_in;
    const int*   elem  = (const int*)d_in[0];
    const int*   eidx  = (const int*)d_in[1];
    const float* dist  = (const float*)d_in[2];
    const int*   pidx  = (const int*)d_in[3];
    const float* embed = (const float*)d_in[4];
    const float* fw1   = (const float*)d_in[5];
    const float* fb1   = (const float*)d_in[6];
    const float* fw2   = (const float*)d_in[7];
    const float* fb2   = (const float*)d_in[8];
    const float* mw1   = (const float*)d_in[9];
    const float* mb1   = (const float*)d_in[10];
    const float* mw2   = (const float*)d_in[11];
    const float* mb2   = (const float*)d_in[12];
    const float* cb    = (const float*)d_in[13];
    const float* rD    = (const float*)d_in[14];
    const float* rA    = (const float*)d_in[15];
    const float* rR    = (const float*)d_in[16];

    int N = in_sizes[0];
    int E = in_sizes[2];
    const int* src = eidx;
    const int* tgt = eidx + E;
    int N4 = N * 4;

    // bucket geometry: nodes/bucket = 2^SHIFT, <=256 buckets, bins <= 2048
    int SHIFT = 0;
    while ((1 << SHIFT) < (N + 255) / 256) SHIFT++;
    int NBUK = (N + (1 << SHIFT) - 1) >> SHIFT;
    long long expv = ((long long)E << SHIFT) / N;        // mean bucket size
    int CAP = (int)(expv + expv / 16 + 256);             // ~ +10 sigma

    // ---- big scratch lives in d_out (dead before k_table/k_out write it) ----
    size_t outBytes = (size_t)out_size * 4;
    char* ob = (char*)d_out;
    size_t oc = 0;
    float* dBuf = (float*)(ob + oc);           oc += (size_t)NBUK * CAP * 4;
    unsigned short* kBuf = (unsigned short*)(ob + oc); oc += (size_t)NBUK * CAP * 2;
    oc = (oc + 3) & ~(size_t)3;
    float* payload = (float*)(ob + oc);        oc += (size_t)E * 4;
    int*   offs4   = (int*)(ob + oc);          oc += (size_t)(N4 + 1) * 4;
    if (oc > outBytes) return;                 // capacity guard

    // ---- small scratch in ws ----
    char* ws = (char*)d_ws;
    size_t cur = 0;
    int*   gCursor    = (int*)(ws + cur);  cur += 256 * 4;
    float* loss       = (float*)(ws + cur); cur += 4;      // memset with gCursor
    size_t clearB = cur;
    int*   bucketBase = (int*)(ws + cur);  cur += 256 * 4;
    int*   atype      = (int*)(ws + cur);  cur += (size_t)N * 4;
    cur = (cur + 15) & ~(size_t)15;
    float4* table     = (float4*)(ws + cur); cur += 2560 * sizeof(float4);
    if (ws_size < cur) return;

    hipMemsetAsync(d_ws, 0, clearB, stream);   // gCursor + loss

    k_bucket<<<(E + EPB - 1) / EPB, 256, 0, stream>>>(
        src, tgt, elem, dist, gCursor, dBuf, kBuf, CAP, SHIFT, E);
    k_bscan<<<1, 256, 0, stream>>>(gCursor, bucketBase, offs4, NBUK, N4, E);
    k_bin<<<NBUK, 256, 0, stream>>>(dBuf, kBuf, gCursor, bucketBase,
                                    offs4, payload, CAP, SHIFT, N);
    k_gather<<<(N + 31) / 32, 256, 0, stream>>>(elem, embed, cb, fw1, fb1,
                                                fw2, fb2, offs4, payload,
                                                atype, loss, N);
    float* outl = (float*)d_out + (size_t)3 * E;
    k_table<<<1, 256, 0, stream>>>(cb, mw1, mb1, mw2, mb2, rD, rA, rR,
                                   loss, table, outl,
                                   1.0f / (float)((size_t)N * 16));
    k_out<<<(E / 2 + 255) / 256, 256, 0, stream>>>(src, tgt, pidx, atype, table,
                                                   (float2*)d_out, E / 2);
}

// Round 11
// 259.716 us; speedup vs baseline: 8.5843x; 1.1644x over previous
//
#include <hip/hip_runtime.h>
#include <stdint.h>

#define A2B   1.8897259886f
#define R_MIN (0.5f * A2B)
#define R_MAX (4.0f * A2B)

#define EPB 2048      // edges per k_bucket block

// ---------------------------------------------------------------------------
// K1: bucket multisplit pass A (UNCHANGED from round 10).
// ---------------------------------------------------------------------------
__global__ void __launch_bounds__(256) k_bucket(
        const int* __restrict__ src, const int* __restrict__ tgt,
        const int* __restrict__ elem, const float* __restrict__ dist,
        int* __restrict__ gCursor, float* __restrict__ dBuf,
        unsigned short* __restrict__ kBuf, int CAP, int SHIFT, int E)
{
    __shared__ int cnt[256], base_[256];
    int t = threadIdx.x;
    cnt[t] = 0;
    __syncthreads();
    int e0 = blockIdx.x * EPB;
    int eEnd = (e0 + EPB < E) ? e0 + EPB : E;

    float dv[8]; int bv[8]; unsigned short kv[8];
    #pragma unroll
    for (int j = 0; j < 8; ++j) {
        int e = e0 + t + j * 256;
        if (e < eEnd) {
            int s = src[e];
            int q = elem[tgt[e]];
            dv[j] = dist[e];
            int b = s >> SHIFT;
            bv[j] = b;
            kv[j] = (unsigned short)(((s - (b << SHIFT)) << 2) | q);
            atomicAdd(&cnt[b], 1);
        }
    }
    __syncthreads();
    if (cnt[t] > 0) base_[t] = atomicAdd(&gCursor[t], cnt[t]);
    __syncthreads();
    cnt[t] = 0;                       // reuse as block-local cursor
    __syncthreads();
    #pragma unroll
    for (int j = 0; j < 8; ++j) {
        int e = e0 + t + j * 256;
        if (e < eEnd) {
            int b = bv[j];
            int pos = base_[b] + atomicAdd(&cnt[b], 1);
            if (pos < CAP) {          // statistically never (CAP = mean+10sd)
                size_t idx = (size_t)b * CAP + pos;
                dBuf[idx] = dv[j];
                kBuf[idx] = kv[j];
            }
        }
    }
}

// ---------------------------------------------------------------------------
// K2: tiny scan of bucket counts -> bucket bases; also offs[N] = E
// ---------------------------------------------------------------------------
__global__ void __launch_bounds__(256) k_bscan(
        const int* __restrict__ gCursor, int* __restrict__ bucketBase,
        int* __restrict__ offs, int NBUK, int N, int E)
{
    __shared__ int sd[256];
    int t = threadIdx.x;
    int v = (t < NBUK) ? gCursor[t] : 0;
    sd[t] = v; __syncthreads();
    #pragma unroll
    for (int o = 1; o < 256; o <<= 1) {
        int x = (t >= o) ? sd[t - o] : 0;
        __syncthreads();
        sd[t] += x;
        __syncthreads();
    }
    bucketBase[t] = sd[t] - v;        // exclusive
    if (t == 0) offs[N] = E;
}

// ---------------------------------------------------------------------------
// K3: pass B. One block per bucket: bin by NODE only (<=512 bins); q is
//     packed into the low 2 mantissa bits of d in the payload (<=4 ulp
//     perturbation, ~2e-6 relative -- negligible through the RBF).
//     Writes per-node CSR offs[N+1]. Zero global atomics.
// ---------------------------------------------------------------------------
__global__ void __launch_bounds__(256) k_bin(
        const float* __restrict__ dBuf, const unsigned short* __restrict__ kBuf,
        const int* __restrict__ gCursor, const int* __restrict__ bucketBase,
        int* __restrict__ offs, float* __restrict__ payload,
        int CAP, int SHIFT, int N)
{
    __shared__ int lcnt[512];
    __shared__ int sd[256];
    int t = threadIdx.x, b = blockIdx.x;
    int n0 = b << SHIFT;
    int n1 = n0 + (1 << SHIFT); if (n1 > N) n1 = N;
    int m  = n1 - n0;
    int cntE = gCursor[b]; if (cntE > CAP) cntE = CAP;
    int base = bucketBase[b];
    for (int i = t; i < m; i += 256) lcnt[i] = 0;
    __syncthreads();
    const float* dB = dBuf + (size_t)b * CAP;
    const unsigned short* kB = kBuf + (size_t)b * CAP;
    for (int i = t; i < cntE; i += 256)
        atomicAdd(&lcnt[kB[i] >> 2], 1);
    __syncthreads();
    // exclusive scan over m<=512 bins, 2 per thread, in place
    int b2 = t * 2;
    int v0 = (b2 < m)     ? lcnt[b2]     : 0;
    int v1 = (b2 + 1 < m) ? lcnt[b2 + 1] : 0;
    int tsum = v0 + v1;
    sd[t] = tsum; __syncthreads();
    #pragma unroll
    for (int o = 1; o < 256; o <<= 1) {
        int x = (t >= o) ? sd[t - o] : 0;
        __syncthreads();
        sd[t] += x;
        __syncthreads();
    }
    int run = sd[t] - tsum;
    if (b2 < m)     { lcnt[b2] = run;     offs[n0 + b2] = base + run;     run += v0; }
    if (b2 + 1 < m) { lcnt[b2 + 1] = run; offs[n0 + b2 + 1] = base + run; run += v1; }
    __syncthreads();
    for (int i = t; i < cntE; i += 256) {
        int kv = kB[i];
        int pos = atomicAdd(&lcnt[kv >> 2], 1);
        unsigned db = __float_as_uint(dB[i]);
        payload[base + pos] = __uint_as_float((db & ~3u) | (unsigned)(kv & 3));
    }
}

// ---------------------------------------------------------------------------
// K4: gather, 4 lanes/node, node-merged edge list (q in payload LSBs).
//     Per edge: L1 (paired, ~87% pair-efficiency at 8 edges/lane) + silu +
//     predicated merge into per-q G0..G3 (static indexing). Then shfl-reduce
//     G+counts across the 4 lanes, q-split affine L2 (lane sub handles q=sub),
//     acc shfl-reduce -> all lanes hold h. VQ unchanged.
//     Register note (r4-r7): NO min-waves cap -- caps forced spills.
// ---------------------------------------------------------------------------
__global__ void __launch_bounds__(256) k_gather(
        const int* __restrict__ elem, const float* __restrict__ embed,
        const float* __restrict__ codebook,
        const float* __restrict__ fw1, const float* __restrict__ fb1,
        const float* __restrict__ fw2, const float* __restrict__ fb2,
        const int* __restrict__ offs, const float* __restrict__ payload,
        int* __restrict__ atype, float* __restrict__ loss, int N)
{
    __shared__ float4 s_fw1t[64];   // [k][i2/4]: fw1t[k][i2] = fw1[i2][k]
    __shared__ float4 s_fw2v[64];   // [j][i2/4]
    __shared__ float s_cb[256];
    __shared__ float s_fb1[16], s_fb2[16], s_emb[64], s_cbn[16];
    __shared__ float s_red[4];
    int t = threadIdx.x;
    {
        float* f1 = (float*)s_fw1t;
        f1[(t & 15) * 16 + (t >> 4)] = fw1[t];     // transpose on stage
        float* f2 = (float*)s_fw2v;
        f2[t] = fw2[t];
        s_cb[t] = codebook[t];
    }
    if (t < 16) { s_fb1[t] = fb1[t]; s_fb2[t] = fb2[t]; }
    if (t < 64) s_emb[t] = embed[t];
    __syncthreads();
    if (t < 16) {
        float s = 0.f;
        #pragma unroll
        for (int j = 0; j < 16; ++j) { float c = s_cb[t * 16 + j]; s += c * c; }
        s_cbn[t] = s;
    }
    __syncthreads();

    int node = blockIdx.x * 64 + (t >> 2);   // 4 lanes per node, 64 nodes/block
    int sub  = t & 3;
    float lp = 0.0f;
    if (node < N) {
        int o0 = offs[node], o1 = offs[node + 1];
        float G0[16], G1[16], G2[16], G3[16];
        #pragma unroll
        for (int j = 0; j < 16; ++j) { G0[j]=0.f; G1[j]=0.f; G2[j]=0.f; G3[j]=0.f; }
        float c0 = 0.f, c1 = 0.f, c2 = 0.f, c3 = 0.f;

        const float invw   = 16.0f / (R_MAX - R_MIN);            // 1/width
        const float u0base = R_MIN * invw;                       // offset
        const float kstep  = 16.0f / 15.0f;                      // step*invw
        for (int i = o0 + sub; i < o1; i += 8) {
            int ii = i + 4;
            bool has2 = (ii < o1);
            unsigned p0 = __float_as_uint(payload[i]);
            unsigned p1 = has2 ? __float_as_uint(payload[ii]) : p0;
            int q0 = (int)(p0 & 3u), q1 = (int)(p1 & 3u);
            float d0 = __uint_as_float(p0 & ~3u);
            float d1 = __uint_as_float(p1 & ~3u);
            float ua = d0 * invw - u0base;
            float ub = d1 * invw - u0base;
            float g0[16], g1[16];
            #pragma unroll
            for (int i2 = 0; i2 < 16; ++i2) { g0[i2] = s_fb1[i2]; g1[i2] = s_fb1[i2]; }
            #pragma clang loop unroll(disable)
            for (int k = 0; k < 16; ++k) {
                float r0 = __expf(-0.5f * ua * ua);
                float r1 = __expf(-0.5f * ub * ub);
                float4 w0 = s_fw1t[k*4+0], w1 = s_fw1t[k*4+1];
                float4 w2 = s_fw1t[k*4+2], w3 = s_fw1t[k*4+3];
                g0[0]+=r0*w0.x;  g0[1]+=r0*w0.y;  g0[2]+=r0*w0.z;  g0[3]+=r0*w0.w;
                g0[4]+=r0*w1.x;  g0[5]+=r0*w1.y;  g0[6]+=r0*w1.z;  g0[7]+=r0*w1.w;
                g0[8]+=r0*w2.x;  g0[9]+=r0*w2.y;  g0[10]+=r0*w2.z; g0[11]+=r0*w2.w;
                g0[12]+=r0*w3.x; g0[13]+=r0*w3.y; g0[14]+=r0*w3.z; g0[15]+=r0*w3.w;
                g1[0]+=r1*w0.x;  g1[1]+=r1*w0.y;  g1[2]+=r1*w0.z;  g1[3]+=r1*w0.w;
                g1[4]+=r1*w1.x;  g1[5]+=r1*w1.y;  g1[6]+=r1*w1.z;  g1[7]+=r1*w1.w;
                g1[8]+=r1*w2.x;  g1[9]+=r1*w2.y;  g1[10]+=r1*w2.z; g1[11]+=r1*w2.w;
                g1[12]+=r1*w3.x; g1[13]+=r1*w3.y; g1[14]+=r1*w3.z; g1[15]+=r1*w3.w;
                ua -= kstep; ub -= kstep;
            }
            {
                float m0 = (q0==0)?1.f:0.f, m1 = (q0==1)?1.f:0.f;
                float m2 = (q0==2)?1.f:0.f, m3 = (q0==3)?1.f:0.f;
                c0 += m0; c1 += m1; c2 += m2; c3 += m3;
                #pragma unroll
                for (int i2 = 0; i2 < 16; ++i2) {
                    float a = g0[i2];
                    float s = a * __builtin_amdgcn_rcpf(1.0f + __expf(-a));
                    G0[i2] += m0*s; G1[i2] += m1*s; G2[i2] += m2*s; G3[i2] += m3*s;
                }
            }
            if (has2) {
                float m0 = (q1==0)?1.f:0.f, m1 = (q1==1)?1.f:0.f;
                float m2 = (q1==2)?1.f:0.f, m3 = (q1==3)?1.f:0.f;
                c0 += m0; c1 += m1; c2 += m2; c3 += m3;
                #pragma unroll
                for (int i2 = 0; i2 < 16; ++i2) {
                    float a = g1[i2];
                    float s = a * __builtin_amdgcn_rcpf(1.0f + __expf(-a));
                    G0[i2] += m0*s; G1[i2] += m1*s; G2[i2] += m2*s; G3[i2] += m3*s;
                }
            }
        }
        // reduce G + counts across the 4 lanes (xor 1,2: stays in group)
        #pragma unroll
        for (int mm = 1; mm <= 2; mm <<= 1) {
            #pragma unroll
            for (int j = 0; j < 16; ++j) {
                G0[j] += __shfl_xor(G0[j], mm, 64);
                G1[j] += __shfl_xor(G1[j], mm, 64);
                G2[j] += __shfl_xor(G2[j], mm, 64);
                G3[j] += __shfl_xor(G3[j], mm, 64);
            }
            c0 += __shfl_xor(c0, mm, 64);
            c1 += __shfl_xor(c1, mm, 64);
            c2 += __shfl_xor(c2, mm, 64);
            c3 += __shfl_xor(c3, mm, 64);
        }
        // lane sub applies affine L2 for q = sub only
        float Gs[16];
        #pragma unroll
        for (int j = 0; j < 16; ++j)
            Gs[j] = (sub==0) ? G0[j] : (sub==1) ? G1[j] : (sub==2) ? G2[j] : G3[j];
        float cs = (sub==0) ? c0 : (sub==1) ? c1 : (sub==2) ? c2 : c3;
        const float* er = s_emb + sub * 16;
        float acc[16];
        #pragma clang loop unroll_count(4)
        for (int j = 0; j < 16; ++j) {
            float4 f0 = s_fw2v[j*4+0], f1 = s_fw2v[j*4+1];
            float4 f2 = s_fw2v[j*4+2], f3 = s_fw2v[j*4+3];
            float w = Gs[0]*f0.x  + Gs[1]*f0.y  + Gs[2]*f0.z  + Gs[3]*f0.w
                    + Gs[4]*f1.x  + Gs[5]*f1.y  + Gs[6]*f1.z  + Gs[7]*f1.w
                    + Gs[8]*f2.x  + Gs[9]*f2.y  + Gs[10]*f2.z + Gs[11]*f2.w
                    + Gs[12]*f3.x + Gs[13]*f3.y + Gs[14]*f3.z + Gs[15]*f3.w;
            acc[j] = (w + cs * s_fb2[j]) * er[j];
        }
        // reduce acc across the 4 lanes -> every lane holds full agg
        #pragma unroll
        for (int mm = 1; mm <= 2; mm <<= 1) {
            #pragma unroll
            for (int j = 0; j < 16; ++j)
                acc[j] += __shfl_xor(acc[j], mm, 64);
        }
        int qn = elem[node];
        float h[16], hh = 0.f;
        #pragma unroll
        for (int j = 0; j < 16; ++j) {
            h[j] = acc[j] + s_emb[qn * 16 + j];
            hh += h[j] * h[j];
        }
        float best = __builtin_inff(); int bi = 0;
        #pragma unroll
        for (int c = 0; c < 4; ++c) {
            int code = qn * 4 + c;
            float dot = 0.f;
            #pragma unroll
            for (int j = 0; j < 16; ++j) dot += h[j] * s_cb[code * 16 + j];
            float d2 = hh - 2.0f * dot + s_cbn[code];
            if (d2 < best) { best = d2; bi = code; }
        }
        if (sub == 0) {
            atype[node] = bi;
            #pragma unroll
            for (int j = 0; j < 16; ++j) {
                float df = h[j] - s_cb[bi * 16 + j];
                lp += df * df;
            }
        }
    }
    // block reduction of loss partials
    #pragma unroll
    for (int o = 32; o > 0; o >>= 1) lp += __shfl_down(lp, o, 64);
    int wid = t >> 6;
    if ((t & 63) == 0) s_red[wid] = lp;
    __syncthreads();
    if (t == 0) atomicAdd(loss, s_red[0] + s_red[1] + s_red[2] + s_red[3]);
}

// ---------------------------------------------------------------------------
// K5: build the 2560-entry (combo x pair) output table; finalize vq_loss
// ---------------------------------------------------------------------------
__global__ void __launch_bounds__(256) k_table(
        const float* __restrict__ codebook,
        const float* __restrict__ mw1, const float* __restrict__ mb1,
        const float* __restrict__ mw2, const float* __restrict__ mb2,
        const float* __restrict__ rD, const float* __restrict__ rA,
        const float* __restrict__ rR,
        const float* __restrict__ loss, float4* __restrict__ table,
        float* __restrict__ out_loss, float inv_nd)
{
    __shared__ float s_cb[256], s_mw1[256], s_mb1[16], s_mw2[48], s_mb2[3];
    __shared__ float s_rd[10], s_ra[10], s_rr[10];
    int tid = threadIdx.x;
    s_cb[tid] = codebook[tid];
    s_mw1[tid] = mw1[tid];
    if (tid < 16) s_mb1[tid] = mb1[tid];
    if (tid < 48) s_mw2[tid] = mw2[tid];
    if (tid < 3)  s_mb2[tid] = mb2[tid];
    if (tid < 10) { s_rd[tid] = rD[tid]; s_ra[tid] = rA[tid]; s_rr[tid] = rR[tid]; }
    __syncthreads();

    int a = tid >> 4, b = tid & 15;
    float pf[16];
    #pragma unroll
    for (int j = 0; j < 16; ++j) pf[j] = s_cb[a * 16 + j] + s_cb[b * 16 + j];
    float hid[16];
    #pragma unroll
    for (int i = 0; i < 16; ++i) {
        float acc = s_mb1[i];
        #pragma unroll
        for (int j = 0; j < 16; ++j) acc += pf[j] * s_mw1[i * 16 + j];
        hid[i] = acc / (1.0f + __expf(-acc));
    }
    float del[3];
    #pragma unroll
    for (int r = 0; r < 3; ++r) {
        float acc = s_mb2[r];
        #pragma unroll
        for (int i = 0; i < 16; ++i) acc += hid[i] * s_mw2[r * 16 + i];
        del[r] = acc;
    }
    #pragma unroll
    for (int p = 0; p < 10; ++p) {
        float xd = s_rd[p] + del[0];
        float xa = s_ra[p] + del[1];
        float De = (xd > 20.f) ? xd : log1pf(__expf(xd));   // softplus
        float al = (xa > 20.f) ? xa : log1pf(__expf(xa));
        float r0 = s_rr[p] + del[2];
        table[tid * 10 + p] = make_float4(De, al, r0, 0.f);
    }
    if (tid == 0) out_loss[0] = 0.25f * loss[0] * inv_nd;
}

// ---------------------------------------------------------------------------
// K6: per-edge output = table[(at[src]*16 + at[tgt])*10 + pair_idx]
// ---------------------------------------------------------------------------
__global__ void __launch_bounds__(256) k_out(
        const int* __restrict__ src, const int* __restrict__ tgt,
        const int* __restrict__ pidx, const int* __restrict__ atype,
        const float4* __restrict__ table, float2* __restrict__ out, int Ehalf)
{
    int i = blockIdx.x * 256 + threadIdx.x;
    if (i >= Ehalf) return;
    int2 s2 = ((const int2*)src)[i];
    int2 t2 = ((const int2*)tgt)[i];
    int2 p2 = ((const int2*)pidx)[i];
    int i0 = (atype[s2.x] * 16 + atype[t2.x]) * 10 + p2.x;
    int i1 = (atype[s2.y] * 16 + atype[t2.y]) * 10 + p2.y;
    float4 t0 = table[i0];
    float4 t1 = table[i1];
    float2* op = out + (size_t)3 * i;
    op[0] = make_float2(t0.x, t0.y);
    op[1] = make_float2(t0.z, t1.x);
    op[2] = make_float2(t1.y, t1.z);
}

// ---------------------------------------------------------------------------
extern "C" void kernel_launch(void* const* d_in, const int* in_sizes, int n_in,
                              void* d_out, int out_size, void* d_ws, size_t ws_size,
                              hipStream_t stream)
{
    (void)n_in;
    const int*   elem  = (const int*)d_in[0];
    const int*   eidx  = (const int*)d_in[1];
    const float* dist  = (const float*)d_in[2];
    const int*   pidx  = (const int*)d_in[3];
    const float* embed = (const float*)d_in[4];
    const float* fw1   = (const float*)d_in[5];
    const float* fb1   = (const float*)d_in[6];
    const float* fw2   = (const float*)d_in[7];
    const float* fb2   = (const float*)d_in[8];
    const float* mw1   = (const float*)d_in[9];
    const float* mb1   = (const float*)d_in[10];
    const float* mw2   = (const float*)d_in[11];
    const float* mb2   = (const float*)d_in[12];
    const float* cb    = (const float*)d_in[13];
    const float* rD    = (const float*)d_in[14];
    const float* rA    = (const float*)d_in[15];
    const float* rR    = (const float*)d_in[16];

    int N = in_sizes[0];
    int E = in_sizes[2];
    const int* src = eidx;
    const int* tgt = eidx + E;

    // bucket geometry: nodes/bucket = 2^SHIFT, <=256 buckets, bins <= 512
    int SHIFT = 0;
    while ((1 << SHIFT) < (N + 255) / 256) SHIFT++;
    int NBUK = (N + (1 << SHIFT) - 1) >> SHIFT;
    long long expv = ((long long)E << SHIFT) / N;        // mean bucket size
    int CAP = (int)(expv + expv / 16 + 256);             // ~ +10 sigma

    // ---- big scratch lives in d_out (dead before k_table/k_out write it) ----
    size_t outBytes = (size_t)out_size * 4;
    char* ob = (char*)d_out;
    size_t oc = 0;
    float* dBuf = (float*)(ob + oc);           oc += (size_t)NBUK * CAP * 4;
    unsigned short* kBuf = (unsigned short*)(ob + oc); oc += (size_t)NBUK * CAP * 2;
    oc = (oc + 3) & ~(size_t)3;
    float* payload = (float*)(ob + oc);        oc += (size_t)E * 4;
    int*   offs    = (int*)(ob + oc);          oc += (size_t)(N + 1) * 4;
    if (oc > outBytes) return;                 // capacity guard

    // ---- small scratch in ws ----
    char* ws = (char*)d_ws;
    size_t cur = 0;
    int*   gCursor    = (int*)(ws + cur);  cur += 256 * 4;
    float* loss       = (float*)(ws + cur); cur += 4;      // memset with gCursor
    size_t clearB = cur;
    int*   bucketBase = (int*)(ws + cur);  cur += 256 * 4;
    int*   atype      = (int*)(ws + cur);  cur += (size_t)N * 4;
    cur = (cur + 15) & ~(size_t)15;
    float4* table     = (float4*)(ws + cur); cur += 2560 * sizeof(float4);
    if (ws_size < cur) return;

    hipMemsetAsync(d_ws, 0, clearB, stream);   // gCursor + loss

    k_bucket<<<(E + EPB - 1) / EPB, 256, 0, stream>>>(
        src, tgt, elem, dist, gCursor, dBuf, kBuf, CAP, SHIFT, E);
    k_bscan<<<1, 256, 0, stream>>>(gCursor, bucketBase, offs, NBUK, N, E);
    k_bin<<<NBUK, 256, 0, stream>>>(dBuf, kBuf, gCursor, bucketBase,
                                    offs, payload, CAP, SHIFT, N);
    k_gather<<<(N + 63) / 64, 256, 0, stream>>>(elem, embed, cb, fw1, fb1,
                                                fw2, fb2, offs, payload,
                                                atype, loss, N);
    float* outl = (float*)d_out + (size_t)3 * E;
    k_table<<<1, 256, 0, stream>>>(cb, mw1, mb1, mw2, mb2, rD, rA, rR,
                                   loss, table, outl,
                                   1.0f / (float)((size_t)N * 16));
    k_out<<<(E / 2 + 255) / 256, 256, 0, stream>>>(src, tgt, pidx, atype, table,
                                                   (float2*)d_out, E / 2);
}

// Round 12
// 255.486 us; speedup vs baseline: 8.7264x; 1.0166x over previous
//
#include <hip/hip_runtime.h>
#include <stdint.h>

#define A2B   1.8897259886f
#define R_MIN (0.5f * A2B)
#define R_MAX (4.0f * A2B)

#define EPB 2048      // edges per k_bucket block

// ---------------------------------------------------------------------------
// K1: bucket multisplit pass A. Per-wave split histograms/cursors (4 waves):
//     quarters LDS-atomic same-bin contention vs round 11's shared cnt[256].
// ---------------------------------------------------------------------------
__global__ void __launch_bounds__(256) k_bucket(
        const int* __restrict__ src, const int* __restrict__ tgt,
        const int* __restrict__ elem, const float* __restrict__ dist,
        int* __restrict__ gCursor, float* __restrict__ dBuf,
        unsigned short* __restrict__ kBuf, int CAP, int SHIFT, int E)
{
    __shared__ int cnt[4][256], sbase[4][256];
    int t = threadIdx.x;
    int w = t >> 6;                   // wave id (wave64)
    cnt[0][t] = 0; cnt[1][t] = 0; cnt[2][t] = 0; cnt[3][t] = 0;
    __syncthreads();
    int e0 = blockIdx.x * EPB;
    int eEnd = (e0 + EPB < E) ? e0 + EPB : E;

    float dv[8]; int bv[8]; unsigned short kv[8];
    #pragma unroll
    for (int j = 0; j < 8; ++j) {
        int e = e0 + t + j * 256;
        if (e < eEnd) {
            int s = src[e];
            int q = elem[tgt[e]];
            dv[j] = dist[e];
            int b = s >> SHIFT;
            bv[j] = b;
            kv[j] = (unsigned short)(((s - (b << SHIFT)) << 2) | q);
            atomicAdd(&cnt[w][b], 1);
        }
    }
    __syncthreads();
    {   // thread t owns bucket t: one global atomic, then per-wave bases
        int c0 = cnt[0][t], c1 = cnt[1][t], c2 = cnt[2][t], c3 = cnt[3][t];
        int tot = c0 + c1 + c2 + c3;
        int g = (tot > 0) ? atomicAdd(&gCursor[t], tot) : 0;
        sbase[0][t] = g;
        sbase[1][t] = g + c0;
        sbase[2][t] = g + c0 + c1;
        sbase[3][t] = g + c0 + c1 + c2;
        cnt[0][t] = 0; cnt[1][t] = 0; cnt[2][t] = 0; cnt[3][t] = 0;
    }
    __syncthreads();
    #pragma unroll
    for (int j = 0; j < 8; ++j) {
        int e = e0 + t + j * 256;
        if (e < eEnd) {
            int b = bv[j];
            int pos = sbase[w][b] + atomicAdd(&cnt[w][b], 1);
            if (pos < CAP) {          // statistically never (CAP = mean+10sd)
                size_t idx = (size_t)b * CAP + pos;
                dBuf[idx] = dv[j];
                kBuf[idx] = kv[j];
            }
        }
    }
}

// ---------------------------------------------------------------------------
// K2: tiny scan of bucket counts -> bucket bases; also offs[N] = E
// ---------------------------------------------------------------------------
__global__ void __launch_bounds__(256) k_bscan(
        const int* __restrict__ gCursor, int* __restrict__ bucketBase,
        int* __restrict__ offs, int NBUK, int N, int E)
{
    __shared__ int sd[256];
    int t = threadIdx.x;
    int v = (t < NBUK) ? gCursor[t] : 0;
    sd[t] = v; __syncthreads();
    #pragma unroll
    for (int o = 1; o < 256; o <<= 1) {
        int x = (t >= o) ? sd[t - o] : 0;
        __syncthreads();
        sd[t] += x;
        __syncthreads();
    }
    bucketBase[t] = sd[t] - v;        // exclusive
    if (t == 0) offs[N] = E;
}

// ---------------------------------------------------------------------------
// K3: pass B (UNCHANGED from round 11). Bin by NODE (<=512 bins); q packed
//     into low 2 mantissa bits of d (<=4 ulp). Writes offs[N+1] + payload.
// ---------------------------------------------------------------------------
__global__ void __launch_bounds__(256) k_bin(
        const float* __restrict__ dBuf, const unsigned short* __restrict__ kBuf,
        const int* __restrict__ gCursor, const int* __restrict__ bucketBase,
        int* __restrict__ offs, float* __restrict__ payload,
        int CAP, int SHIFT, int N)
{
    __shared__ int lcnt[512];
    __shared__ int sd[256];
    int t = threadIdx.x, b = blockIdx.x;
    int n0 = b << SHIFT;
    int n1 = n0 + (1 << SHIFT); if (n1 > N) n1 = N;
    int m  = n1 - n0;
    int cntE = gCursor[b]; if (cntE > CAP) cntE = CAP;
    int base = bucketBase[b];
    for (int i = t; i < m; i += 256) lcnt[i] = 0;
    __syncthreads();
    const float* dB = dBuf + (size_t)b * CAP;
    const unsigned short* kB = kBuf + (size_t)b * CAP;
    for (int i = t; i < cntE; i += 256)
        atomicAdd(&lcnt[kB[i] >> 2], 1);
    __syncthreads();
    int b2 = t * 2;
    int v0 = (b2 < m)     ? lcnt[b2]     : 0;
    int v1 = (b2 + 1 < m) ? lcnt[b2 + 1] : 0;
    int tsum = v0 + v1;
    sd[t] = tsum; __syncthreads();
    #pragma unroll
    for (int o = 1; o < 256; o <<= 1) {
        int x = (t >= o) ? sd[t - o] : 0;
        __syncthreads();
        sd[t] += x;
        __syncthreads();
    }
    int run = sd[t] - tsum;
    if (b2 < m)     { lcnt[b2] = run;     offs[n0 + b2] = base + run;     run += v0; }
    if (b2 + 1 < m) { lcnt[b2 + 1] = run; offs[n0 + b2 + 1] = base + run; run += v1; }
    __syncthreads();
    for (int i = t; i < cntE; i += 256) {
        int kv = kB[i];
        int pos = atomicAdd(&lcnt[kv >> 2], 1);
        unsigned db = __float_as_uint(dB[i]);
        payload[base + pos] = __uint_as_float((db & ~3u) | (unsigned)(kv & 3));
    }
}

// ---------------------------------------------------------------------------
// K4: gather, 4 lanes/node. NEW: block bitonic-sorts its 64 nodes by degree
//     so each wave's 16 lane-groups have near-equal trip counts (kills the
//     ~40% masked-issue waste from E[max of 16 Poisson(32)] ~ 45 vs mean 32).
//     Math per node identical to round 11 (same edge order, same ops).
//     Register note (r4-r7): NO min-waves cap -- caps forced spills.
// ---------------------------------------------------------------------------
__global__ void __launch_bounds__(256) k_gather(
        const int* __restrict__ elem, const float* __restrict__ embed,
        const float* __restrict__ codebook,
        const float* __restrict__ fw1, const float* __restrict__ fb1,
        const float* __restrict__ fw2, const float* __restrict__ fb2,
        const int* __restrict__ offs, const float* __restrict__ payload,
        int* __restrict__ atype, float* __restrict__ loss, int N)
{
    __shared__ float4 s_fw1t[64];   // [k][i2/4]: fw1t[k][i2] = fw1[i2][k]
    __shared__ float4 s_fw2v[64];   // [j][i2/4]
    __shared__ float s_cb[256];
    __shared__ float s_fb1[16], s_fb2[16], s_emb[64], s_cbn[16];
    __shared__ float s_red[4];
    __shared__ int s_ord[64];
    int t = threadIdx.x;
    {
        float* f1 = (float*)s_fw1t;
        f1[(t & 15) * 16 + (t >> 4)] = fw1[t];     // transpose on stage
        float* f2 = (float*)s_fw2v;
        f2[t] = fw2[t];
        s_cb[t] = codebook[t];
    }
    if (t < 16) { s_fb1[t] = fb1[t]; s_fb2[t] = fb2[t]; }
    if (t < 64) s_emb[t] = embed[t];
    int nbase = blockIdx.x * 64;
    if (t < 64) {
        int n = nbase + t;
        int dg = (n < N) ? (offs[n + 1] - offs[n]) : 0x7FFF;  // sentinel->end
        s_ord[t] = (dg << 6) | t;
    }
    __syncthreads();
    if (t < 16) {
        float s = 0.f;
        #pragma unroll
        for (int j = 0; j < 16; ++j) { float c = s_cb[t * 16 + j]; s += c * c; }
        s_cbn[t] = s;
    }
    // bitonic sort of 64 (deg,local) keys, threads 0..63
    for (int ksz = 2; ksz <= 64; ksz <<= 1) {
        for (int jj = ksz >> 1; jj > 0; jj >>= 1) {
            __syncthreads();
            if (t < 64) {
                int ixj = t ^ jj;
                if (ixj > t) {
                    int a = s_ord[t], b = s_ord[ixj];
                    bool asc = ((t & ksz) == 0);
                    if (asc ? (a > b) : (a < b)) { s_ord[t] = b; s_ord[ixj] = a; }
                }
            }
        }
    }
    __syncthreads();

    int node = nbase + (s_ord[t >> 2] & 63);   // degree-matched groups/wave
    int sub  = t & 3;
    float lp = 0.0f;
    if (node < N) {
        int o0 = offs[node], o1 = offs[node + 1];
        float G0[16], G1[16], G2[16], G3[16];
        #pragma unroll
        for (int j = 0; j < 16; ++j) { G0[j]=0.f; G1[j]=0.f; G2[j]=0.f; G3[j]=0.f; }
        float c0 = 0.f, c1 = 0.f, c2 = 0.f, c3 = 0.f;

        const float invw   = 16.0f / (R_MAX - R_MIN);            // 1/width
        const float u0base = R_MIN * invw;                       // offset
        const float kstep  = 16.0f / 15.0f;                      // step*invw
        for (int i = o0 + sub; i < o1; i += 8) {
            int ii = i + 4;
            bool has2 = (ii < o1);
            unsigned p0 = __float_as_uint(payload[i]);
            unsigned p1 = has2 ? __float_as_uint(payload[ii]) : p0;
            int q0 = (int)(p0 & 3u), q1 = (int)(p1 & 3u);
            float d0 = __uint_as_float(p0 & ~3u);
            float d1 = __uint_as_float(p1 & ~3u);
            float ua = d0 * invw - u0base;
            float ub = d1 * invw - u0base;
            float g0[16], g1[16];
            #pragma unroll
            for (int i2 = 0; i2 < 16; ++i2) { g0[i2] = s_fb1[i2]; g1[i2] = s_fb1[i2]; }
            #pragma clang loop unroll(disable)
            for (int k = 0; k < 16; ++k) {
                float r0 = __expf(-0.5f * ua * ua);
                float r1 = __expf(-0.5f * ub * ub);
                float4 w0 = s_fw1t[k*4+0], w1 = s_fw1t[k*4+1];
                float4 w2 = s_fw1t[k*4+2], w3 = s_fw1t[k*4+3];
                g0[0]+=r0*w0.x;  g0[1]+=r0*w0.y;  g0[2]+=r0*w0.z;  g0[3]+=r0*w0.w;
                g0[4]+=r0*w1.x;  g0[5]+=r0*w1.y;  g0[6]+=r0*w1.z;  g0[7]+=r0*w1.w;
                g0[8]+=r0*w2.x;  g0[9]+=r0*w2.y;  g0[10]+=r0*w2.z; g0[11]+=r0*w2.w;
                g0[12]+=r0*w3.x; g0[13]+=r0*w3.y; g0[14]+=r0*w3.z; g0[15]+=r0*w3.w;
                g1[0]+=r1*w0.x;  g1[1]+=r1*w0.y;  g1[2]+=r1*w0.z;  g1[3]+=r1*w0.w;
                g1[4]+=r1*w1.x;  g1[5]+=r1*w1.y;  g1[6]+=r1*w1.z;  g1[7]+=r1*w1.w;
                g1[8]+=r1*w2.x;  g1[9]+=r1*w2.y;  g1[10]+=r1*w2.z; g1[11]+=r1*w2.w;
                g1[12]+=r1*w3.x; g1[13]+=r1*w3.y; g1[14]+=r1*w3.z; g1[15]+=r1*w3.w;
                ua -= kstep; ub -= kstep;
            }
            {
                float m0 = (q0==0)?1.f:0.f, m1 = (q0==1)?1.f:0.f;
                float m2 = (q0==2)?1.f:0.f, m3 = (q0==3)?1.f:0.f;
                c0 += m0; c1 += m1; c2 += m2; c3 += m3;
                #pragma unroll
                for (int i2 = 0; i2 < 16; ++i2) {
                    float a = g0[i2];
                    float s = a * __builtin_amdgcn_rcpf(1.0f + __expf(-a));
                    G0[i2] += m0*s; G1[i2] += m1*s; G2[i2] += m2*s; G3[i2] += m3*s;
                }
            }
            if (has2) {
                float m0 = (q1==0)?1.f:0.f, m1 = (q1==1)?1.f:0.f;
                float m2 = (q1==2)?1.f:0.f, m3 = (q1==3)?1.f:0.f;
                c0 += m0; c1 += m1; c2 += m2; c3 += m3;
                #pragma unroll
                for (int i2 = 0; i2 < 16; ++i2) {
                    float a = g1[i2];
                    float s = a * __builtin_amdgcn_rcpf(1.0f + __expf(-a));
                    G0[i2] += m0*s; G1[i2] += m1*s; G2[i2] += m2*s; G3[i2] += m3*s;
                }
            }
        }
        // reduce G + counts across the 4 lanes (xor 1,2: stays in group)
        #pragma unroll
        for (int mm = 1; mm <= 2; mm <<= 1) {
            #pragma unroll
            for (int j = 0; j < 16; ++j) {
                G0[j] += __shfl_xor(G0[j], mm, 64);
                G1[j] += __shfl_xor(G1[j], mm, 64);
                G2[j] += __shfl_xor(G2[j], mm, 64);
                G3[j] += __shfl_xor(G3[j], mm, 64);
            }
            c0 += __shfl_xor(c0, mm, 64);
            c1 += __shfl_xor(c1, mm, 64);
            c2 += __shfl_xor(c2, mm, 64);
            c3 += __shfl_xor(c3, mm, 64);
        }
        // lane sub applies affine L2 for q = sub only
        float Gs[16];
        #pragma unroll
        for (int j = 0; j < 16; ++j)
            Gs[j] = (sub==0) ? G0[j] : (sub==1) ? G1[j] : (sub==2) ? G2[j] : G3[j];
        float cs = (sub==0) ? c0 : (sub==1) ? c1 : (sub==2) ? c2 : c3;
        const float* er = s_emb + sub * 16;
        float acc[16];
        #pragma clang loop unroll_count(4)
        for (int j = 0; j < 16; ++j) {
            float4 f0 = s_fw2v[j*4+0], f1 = s_fw2v[j*4+1];
            float4 f2 = s_fw2v[j*4+2], f3 = s_fw2v[j*4+3];
            float w = Gs[0]*f0.x  + Gs[1]*f0.y  + Gs[2]*f0.z  + Gs[3]*f0.w
                    + Gs[4]*f1.x  + Gs[5]*f1.y  + Gs[6]*f1.z  + Gs[7]*f1.w
                    + Gs[8]*f2.x  + Gs[9]*f2.y  + Gs[10]*f2.z + Gs[11]*f2.w
                    + Gs[12]*f3.x + Gs[13]*f3.y + Gs[14]*f3.z + Gs[15]*f3.w;
            acc[j] = (w + cs * s_fb2[j]) * er[j];
        }
        // reduce acc across the 4 lanes -> every lane holds full agg
        #pragma unroll
        for (int mm = 1; mm <= 2; mm <<= 1) {
            #pragma unroll
            for (int j = 0; j < 16; ++j)
                acc[j] += __shfl_xor(acc[j], mm, 64);
        }
        int qn = elem[node];
        float h[16], hh = 0.f;
        #pragma unroll
        for (int j = 0; j < 16; ++j) {
            h[j] = acc[j] + s_emb[qn * 16 + j];
            hh += h[j] * h[j];
        }
        float best = __builtin_inff(); int bi = 0;
        #pragma unroll
        for (int c = 0; c < 4; ++c) {
            int code = qn * 4 + c;
            float dot = 0.f;
            #pragma unroll
            for (int j = 0; j < 16; ++j) dot += h[j] * s_cb[code * 16 + j];
            float d2 = hh - 2.0f * dot + s_cbn[code];
            if (d2 < best) { best = d2; bi = code; }
        }
        if (sub == 0) {
            atype[node] = bi;
            #pragma unroll
            for (int j = 0; j < 16; ++j) {
                float df = h[j] - s_cb[bi * 16 + j];
                lp += df * df;
            }
        }
    }
    // block reduction of loss partials
    #pragma unroll
    for (int o = 32; o > 0; o >>= 1) lp += __shfl_down(lp, o, 64);
    int wid = t >> 6;
    if ((t & 63) == 0) s_red[wid] = lp;
    __syncthreads();
    if (t == 0) atomicAdd(loss, s_red[0] + s_red[1] + s_red[2] + s_red[3]);
}

// ---------------------------------------------------------------------------
// K5: build the 2560-entry (combo x pair) output table; finalize vq_loss
// ---------------------------------------------------------------------------
__global__ void __launch_bounds__(256) k_table(
        const float* __restrict__ codebook,
        const float* __restrict__ mw1, const float* __restrict__ mb1,
        const float* __restrict__ mw2, const float* __restrict__ mb2,
        const float* __restrict__ rD, const float* __restrict__ rA,
        const float* __restrict__ rR,
        const float* __restrict__ loss, float4* __restrict__ table,
        float* __restrict__ out_loss, float inv_nd)
{
    __shared__ float s_cb[256], s_mw1[256], s_mb1[16], s_mw2[48], s_mb2[3];
    __shared__ float s_rd[10], s_ra[10], s_rr[10];
    int tid = threadIdx.x;
    s_cb[tid] = codebook[tid];
    s_mw1[tid] = mw1[tid];
    if (tid < 16) s_mb1[tid] = mb1[tid];
    if (tid < 48) s_mw2[tid] = mw2[tid];
    if (tid < 3)  s_mb2[tid] = mb2[tid];
    if (tid < 10) { s_rd[tid] = rD[tid]; s_ra[tid] = rA[tid]; s_rr[tid] = rR[tid]; }
    __syncthreads();

    int a = tid >> 4, b = tid & 15;
    float pf[16];
    #pragma unroll
    for (int j = 0; j < 16; ++j) pf[j] = s_cb[a * 16 + j] + s_cb[b * 16 + j];
    float hid[16];
    #pragma unroll
    for (int i = 0; i < 16; ++i) {
        float acc = s_mb1[i];
        #pragma unroll
        for (int j = 0; j < 16; ++j) acc += pf[j] * s_mw1[i * 16 + j];
        hid[i] = acc / (1.0f + __expf(-acc));
    }
    float del[3];
    #pragma unroll
    for (int r = 0; r < 3; ++r) {
        float acc = s_mb2[r];
        #pragma unroll
        for (int i = 0; i < 16; ++i) acc += hid[i] * s_mw2[r * 16 + i];
        del[r] = acc;
    }
    #pragma unroll
    for (int p = 0; p < 10; ++p) {
        float xd = s_rd[p] + del[0];
        float xa = s_ra[p] + del[1];
        float De = (xd > 20.f) ? xd : log1pf(__expf(xd));   // softplus
        float al = (xa > 20.f) ? xa : log1pf(__expf(xa));
        float r0 = s_rr[p] + del[2];
        table[tid * 10 + p] = make_float4(De, al, r0, 0.f);
    }
    if (tid == 0) out_loss[0] = 0.25f * loss[0] * inv_nd;
}

// ---------------------------------------------------------------------------
// K6: per-edge output = table[(at[src]*16 + at[tgt])*10 + pair_idx]
// ---------------------------------------------------------------------------
__global__ void __launch_bounds__(256) k_out(
        const int* __restrict__ src, const int* __restrict__ tgt,
        const int* __restrict__ pidx, const int* __restrict__ atype,
        const float4* __restrict__ table, float2* __restrict__ out, int Ehalf)
{
    int i = blockIdx.x * 256 + threadIdx.x;
    if (i >= Ehalf) return;
    int2 s2 = ((const int2*)src)[i];
    int2 t2 = ((const int2*)tgt)[i];
    int2 p2 = ((const int2*)pidx)[i];
    int i0 = (atype[s2.x] * 16 + atype[t2.x]) * 10 + p2.x;
    int i1 = (atype[s2.y] * 16 + atype[t2.y]) * 10 + p2.y;
    float4 t0 = table[i0];
    float4 t1 = table[i1];
    float2* op = out + (size_t)3 * i;
    op[0] = make_float2(t0.x, t0.y);
    op[1] = make_float2(t0.z, t1.x);
    op[2] = make_float2(t1.y, t1.z);
}

// ---------------------------------------------------------------------------
extern "C" void kernel_launch(void* const* d_in, const int* in_sizes, int n_in,
                              void* d_out, int out_size, void* d_ws, size_t ws_size,
                              hipStream_t stream)
{
    (void)n_in;
    const int*   elem  = (const int*)d_in[0];
    const int*   eidx  = (const int*)d_in[1];
    const float* dist  = (const float*)d_in[2];
    const int*   pidx  = (const int*)d_in[3];
    const float* embed = (const float*)d_in[4];
    const float* fw1   = (const float*)d_in[5];
    const float* fb1   = (const float*)d_in[6];
    const float* fw2   = (const float*)d_in[7];
    const float* fb2   = (const float*)d_in[8];
    const float* mw1   = (const float*)d_in[9];
    const float* mb1   = (const float*)d_in[10];
    const float* mw2   = (const float*)d_in[11];
    const float* mb2   = (const float*)d_in[12];
    const float* cb    = (const float*)d_in[13];
    const float* rD    = (const float*)d_in[14];
    const float* rA    = (const float*)d_in[15];
    const float* rR    = (const float*)d_in[16];

    int N = in_sizes[0];
    int E = in_sizes[2];
    const int* src = eidx;
    const int* tgt = eidx + E;

    // bucket geometry: nodes/bucket = 2^SHIFT, <=256 buckets, bins <= 512
    int SHIFT = 0;
    while ((1 << SHIFT) < (N + 255) / 256) SHIFT++;
    int NBUK = (N + (1 << SHIFT) - 1) >> SHIFT;
    long long expv = ((long long)E << SHIFT) / N;        // mean bucket size
    int CAP = (int)(expv + expv / 16 + 256);             // ~ +10 sigma

    // ---- big scratch lives in d_out (dead before k_table/k_out write it) ----
    size_t outBytes = (size_t)out_size * 4;
    char* ob = (char*)d_out;
    size_t oc = 0;
    float* dBuf = (float*)(ob + oc);           oc += (size_t)NBUK * CAP * 4;
    unsigned short* kBuf = (unsigned short*)(ob + oc); oc += (size_t)NBUK * CAP * 2;
    oc = (oc + 3) & ~(size_t)3;
    float* payload = (float*)(ob + oc);        oc += (size_t)E * 4;
    int*   offs    = (int*)(ob + oc);          oc += (size_t)(N + 1) * 4;
    if (oc > outBytes) return;                 // capacity guard

    // ---- small scratch in ws ----
    char* ws = (char*)d_ws;
    size_t cur = 0;
    int*   gCursor    = (int*)(ws + cur);  cur += 256 * 4;
    float* loss       = (float*)(ws + cur); cur += 4;      // memset with gCursor
    size_t clearB = cur;
    int*   bucketBase = (int*)(ws + cur);  cur += 256 * 4;
    int*   atype      = (int*)(ws + cur);  cur += (size_t)N * 4;
    cur = (cur + 15) & ~(size_t)15;
    float4* table     = (float4*)(ws + cur); cur += 2560 * sizeof(float4);
    if (ws_size < cur) return;

    hipMemsetAsync(d_ws, 0, clearB, stream);   // gCursor + loss

    k_bucket<<<(E + EPB - 1) / EPB, 256, 0, stream>>>(
        src, tgt, elem, dist, gCursor, dBuf, kBuf, CAP, SHIFT, E);
    k_bscan<<<1, 256, 0, stream>>>(gCursor, bucketBase, offs, NBUK, N, E);
    k_bin<<<NBUK, 256, 0, stream>>>(dBuf, kBuf, gCursor, bucketBase,
                                    offs, payload, CAP, SHIFT, N);
    k_gather<<<(N + 63) / 64, 256, 0, stream>>>(elem, embed, cb, fw1, fb1,
                                                fw2, fb2, offs, payload,
                                                atype, loss, N);
    float* outl = (float*)d_out + (size_t)3 * E;
    k_table<<<1, 256, 0, stream>>>(cb, mw1, mb1, mw2, mb2, rD, rA, rR,
                                   loss, table, outl,
                                   1.0f / (float)((size_t)N * 16));
    k_out<<<(E / 2 + 255) / 256, 256, 0, stream>>>(src, tgt, pidx, atype, table,
                                                   (float2*)d_out, E / 2);
}